// Round 2
// baseline (3725.970 us; speedup 1.0000x reference)
//
#include <hip/hip_runtime.h>
#include <stdint.h>

typedef __attribute__((ext_vector_type(4))) float f32x4;
typedef __attribute__((ext_vector_type(8))) short short8;
typedef __attribute__((ext_vector_type(8))) _Float16 half8;

#define DMODEL 512
#define SEQ 513
#define BATCH 128
#define NROWS (BATCH*SEQ)   // 65664 = 513 * 128
#define DHID 682
#define DHID2 1364
#define DH2P 1408
#define DHP 704

__device__ __forceinline__ float h2f(ushort u){ return (float)__builtin_bit_cast(_Float16, u); }
__device__ __forceinline__ ushort f2h(float f){ return __builtin_bit_cast(ushort, (_Float16)f); }
__device__ __forceinline__ f32x4 splat4(float x){ f32x4 v; v[0]=x; v[1]=x; v[2]=x; v[3]=x; return v; }
__device__ __forceinline__ f32x4 max4(f32x4 a, f32x4 b){
  f32x4 r;
#pragma unroll
  for(int i=0;i<4;i++) r[i]=fmaxf(a[i],b[i]);
  return r;
}
__device__ __forceinline__ void gload16(const void* g, void* lds){
  __builtin_amdgcn_global_load_lds((const __attribute__((address_space(1))) void*)g,
                                   (__attribute__((address_space(3))) void*)lds, 16, 0, 0);
}

// ---------------------------------------------------------------------------
// GEMM: C[N x O] = A[N x K] @ W[O x K]^T (+bias). fp16 in, fp32 accum.
// EPI=0: write fp16 C (ldc = O stride). EPI=1: Cf[idx] += acc + bias (fp32).
// Requires N%128==0 (grid.y = N/128), O%128==0 (grid.x = O/128), K%32==0.
// m97 structure: 128x128 tile, BK=32, 4 waves, global_load_lds width 16.
// ---------------------------------------------------------------------------
template<int EPI>
__global__ __launch_bounds__(256,2) void gemm_bt(
    const ushort* __restrict__ A, const ushort* __restrict__ W,
    const float* __restrict__ bias, ushort* __restrict__ Cb, float* __restrict__ Cf,
    int K, int ldc)
{
  __shared__ ushort As[128*32];
  __shared__ ushort Ws[128*32];
  const int t = threadIdx.x;
  const int lane = t & 63, w = t >> 6;
  const int row0 = blockIdx.y << 7, col0 = blockIdx.x << 7;
  const int wr = (w >> 1) << 6, wc = (w & 1) << 6;
  const int srow = (w << 4) + (lane >> 2);   // row within 64-row half
  const int scol = (lane & 3) << 3;          // elem offset in row
  const ushort* Ag = A + (size_t)(row0 + srow) * K + scol;
  const ushort* Wg = W + (size_t)(col0 + srow) * K + scol;
  char* AsB = (char*)As;
  char* WsB = (char*)Ws;
  const int ldsw = w << 10;

  f32x4 acc[4][4] = {};

  for (int k0 = 0; k0 < K; k0 += 32) {
    __syncthreads();
    gload16(Ag + k0,                AsB + ldsw);
    gload16(Ag + (size_t)64*K + k0, AsB + 4096 + ldsw);
    gload16(Wg + k0,                WsB + ldsw);
    gload16(Wg + (size_t)64*K + k0, WsB + 4096 + ldsw);
    __syncthreads();
    const int fr = lane & 15, fo = (lane >> 4) << 3;
    half8 af[4], wf[4];
#pragma unroll
    for (int m = 0; m < 4; ++m) af[m] = *(const half8*)&As[(wr + m*16 + fr)*32 + fo];
#pragma unroll
    for (int n = 0; n < 4; ++n) wf[n] = *(const half8*)&Ws[(wc + n*16 + fr)*32 + fo];
#pragma unroll
    for (int m = 0; m < 4; ++m)
#pragma unroll
      for (int n = 0; n < 4; ++n)
        acc[m][n] = __builtin_amdgcn_mfma_f32_16x16x32_f16(af[m], wf[n], acc[m][n], 0, 0, 0);
  }

  const int fr = lane & 15;
  const int r0 = (lane >> 4) << 2;
#pragma unroll
  for (int m = 0; m < 4; ++m) {
    const int rg = row0 + wr + m*16 + r0;
#pragma unroll
    for (int n = 0; n < 4; ++n) {
      const int cg = col0 + wc + n*16 + fr;
      const float bi = bias[cg];
      if (EPI == 0) {
#pragma unroll
        for (int r = 0; r < 4; ++r)
          Cb[(size_t)(rg + r)*ldc + cg] = f2h(acc[m][n][r] + bi);
      } else {
#pragma unroll
        for (int r = 0; r < 4; ++r) {
          const size_t ix = (size_t)(rg + r)*ldc + cg;
          Cf[ix] += acc[m][n][r] + bi;
        }
      }
    }
  }
}

// ---------------------------------------------------------------------------
// Flash attention (full layers). grid (5 qtiles, 8 heads, 128 batch), 256 thr.
// Each wave: 32 q-rows. K tile 32 keys staged in LDS; V staged transposed.
// Q pre-scaled by 0.125 (exact in fp16). Scores masked beyond SEQ.
// ---------------------------------------------------------------------------
__global__ __launch_bounds__(256,2) void attn_flash(
    const ushort* __restrict__ q, const ushort* __restrict__ k,
    const ushort* __restrict__ v, ushort* __restrict__ o)
{
  const int qt = blockIdx.x, h = blockIdx.y, b = blockIdx.z;
  const int t = threadIdx.x, lane = t & 63, w = t >> 6;
  const size_t rowB = (size_t)b * SEQ;
  __shared__ ushort Ks[32*72];     // [key][72] padded
  __shared__ ushort Vs[64*40];     // V^T: [d][40] padded
  __shared__ ushort Ps[4][32*40];  // per-wave P tile

  const int fr = lane & 15, g = lane >> 4;
  const int qr0 = qt*128 + w*32;

  half8 qf[2][2];
#pragma unroll
  for (int m = 0; m < 2; ++m) {
    const int qrow = qr0 + m*16 + fr;
    const bool ok = qrow < SEQ;
#pragma unroll
    for (int kk = 0; kk < 2; ++kk) {
      short8 val = {0,0,0,0,0,0,0,0};
      if (ok) val = *(const short8*)&q[(rowB + qrow)*DMODEL + h*64 + kk*32 + g*8];
      half8 hv;
#pragma unroll
      for (int j = 0; j < 8; ++j) hv[j] = (_Float16)(h2f((ushort)val[j]) * 0.125f);
      qf[m][kk] = hv;
    }
  }

  f32x4 accO[2][4] = {};
  f32x4 mrun[2], lrun[2];
  mrun[0] = splat4(-1e30f); mrun[1] = splat4(-1e30f);
  lrun[0] = splat4(0.f);    lrun[1] = splat4(0.f);

  const int sKey = t >> 3;          // 0..31
  const int sD = (t & 7) << 3;      // 0..56

  for (int kt = 0; kt < 17; ++kt) {
    __syncthreads();
    const int keyg = kt*32 + sKey;
    short8 kv = {0,0,0,0,0,0,0,0}, vv = {0,0,0,0,0,0,0,0};
    if (keyg < SEQ) {
      kv = *(const short8*)&k[(rowB + keyg)*DMODEL + h*64 + sD];
      vv = *(const short8*)&v[(rowB + keyg)*DMODEL + h*64 + sD];
    }
    *(short8*)&Ks[sKey*72 + sD] = kv;
#pragma unroll
    for (int j = 0; j < 8; ++j) Vs[(sD + j)*40 + sKey] = (ushort)vv[j];
    __syncthreads();

    // scores: C layout: key = lane&15 (+16n), qrow = (lane>>4)*4+r (+16m)
    f32x4 sc[2][2] = {};
#pragma unroll
    for (int kk = 0; kk < 2; ++kk) {
      half8 bfr[2];
#pragma unroll
      for (int n = 0; n < 2; ++n)
        bfr[n] = *(const half8*)&Ks[(n*16 + fr)*72 + kk*32 + g*8];
#pragma unroll
      for (int m = 0; m < 2; ++m)
#pragma unroll
        for (int n = 0; n < 2; ++n)
          sc[m][n] = __builtin_amdgcn_mfma_f32_16x16x32_f16(qf[m][kk], bfr[n], sc[m][n], 0, 0, 0);
    }
#pragma unroll
    for (int n = 0; n < 2; ++n) {
      if (kt*32 + n*16 + fr >= SEQ) { sc[0][n] = splat4(-1e30f); sc[1][n] = splat4(-1e30f); }
    }

#pragma unroll
    for (int m = 0; m < 2; ++m) {
      f32x4 tm = max4(sc[m][0], sc[m][1]);
#pragma unroll
      for (int mask = 1; mask <= 8; mask <<= 1) {
        f32x4 ot;
#pragma unroll
        for (int r = 0; r < 4; ++r) ot[r] = __shfl_xor(tm[r], mask);
        tm = max4(tm, ot);
      }
      f32x4 mnew = max4(mrun[m], tm);
      f32x4 al, p0, p1;
#pragma unroll
      for (int r = 0; r < 4; ++r) {
        al[r] = __expf(mrun[m][r] - mnew[r]);
        p0[r] = __expf(sc[m][0][r] - mnew[r]);
        p1[r] = __expf(sc[m][1][r] - mnew[r]);
      }
      f32x4 rs = p0 + p1;
#pragma unroll
      for (int mask = 1; mask <= 8; mask <<= 1) {
        f32x4 ot;
#pragma unroll
        for (int r = 0; r < 4; ++r) ot[r] = __shfl_xor(rs[r], mask);
        rs += ot;
      }
      lrun[m] = lrun[m]*al + rs;
      mrun[m] = mnew;
#pragma unroll
      for (int n2 = 0; n2 < 4; ++n2) accO[m][n2] *= al;
      ushort* pw = Ps[w];
#pragma unroll
      for (int r = 0; r < 4; ++r) {
        pw[(m*16 + g*4 + r)*40 + fr]      = f2h(p0[r]);
        pw[(m*16 + g*4 + r)*40 + 16 + fr] = f2h(p1[r]);
      }
    }

    half8 pf[2], vf[4];
#pragma unroll
    for (int m = 0; m < 2; ++m) pf[m] = *(const half8*)&Ps[w][(m*16 + fr)*40 + g*8];
#pragma unroll
    for (int n2 = 0; n2 < 4; ++n2) vf[n2] = *(const half8*)&Vs[(n2*16 + fr)*40 + g*8];
#pragma unroll
    for (int m = 0; m < 2; ++m)
#pragma unroll
      for (int n2 = 0; n2 < 4; ++n2)
        accO[m][n2] = __builtin_amdgcn_mfma_f32_16x16x32_f16(pf[m], vf[n2], accO[m][n2], 0, 0, 0);
  }

#pragma unroll
  for (int m = 0; m < 2; ++m)
#pragma unroll
    for (int r = 0; r < 4; ++r) {
      const int qrow = qr0 + m*16 + g*4 + r;
      if (qrow < SEQ) {
        const float inv = 1.f / lrun[m][r];
#pragma unroll
        for (int n2 = 0; n2 < 4; ++n2)
          o[(rowB + qrow)*DMODEL + h*64 + n2*16 + fr] = f2h(accO[m][n2][r] * inv);
      }
    }
}

// ---------------------------------------------------------------------------
// LayerNorm fp32 -> fp16. One wave per row (D=512, 8 elems/lane).
// ---------------------------------------------------------------------------
__global__ __launch_bounds__(256) void ln_kernel(
    const float* __restrict__ x, const float* __restrict__ gamma, const float* __restrict__ beta,
    ushort* __restrict__ out, int nrows)
{
  const int row = blockIdx.x*4 + (threadIdx.x >> 6);
  const int lane = threadIdx.x & 63;
  if (row >= nrows) return;
  const float* xr = x + (size_t)row*DMODEL;
  float4 a = *(const float4*)(xr + lane*8);
  float4 b = *(const float4*)(xr + lane*8 + 4);
  float s  = a.x+a.y+a.z+a.w+b.x+b.y+b.z+b.w;
  float ss = a.x*a.x+a.y*a.y+a.z*a.z+a.w*a.w+b.x*b.x+b.y*b.y+b.z*b.z+b.w*b.w;
#pragma unroll
  for (int mask=1; mask<64; mask<<=1){ s += __shfl_xor(s,mask); ss += __shfl_xor(ss,mask); }
  const float mu = s*(1.f/512.f);
  const float rstd = rsqrtf(ss*(1.f/512.f) - mu*mu + 1e-5f);
  float vals[8] = {a.x,a.y,a.z,a.w,b.x,b.y,b.z,b.w};
  short8 pk;
#pragma unroll
  for (int j=0;j<8;++j){
    const int c = lane*8 + j;
    pk[j] = (short)f2h((vals[j]-mu)*rstd*gamma[c] + beta[c]);
  }
  *(short8*)(out + (size_t)row*DMODEL + lane*8) = pk;
}

// ---------------------------------------------------------------------------
// Embed: x[b,0,:]=cls, x[b,1+t,:]=x_num[b,t,:]; also xb = fp16(x)
// ---------------------------------------------------------------------------
__global__ void embed_kernel(const float* __restrict__ x_num, const float* __restrict__ cls_w,
                             float* __restrict__ x, ushort* __restrict__ xb)
{
  const size_t i = (size_t)blockIdx.x*256 + threadIdx.x;
  if (i >= (size_t)NROWS*128) return;
  const int row = (int)(i >> 7);
  const int c4 = ((int)(i & 127)) << 2;
  const int b = row / SEQ;
  const int s = row - b*SEQ;
  float4 val;
  if (s == 0) val = *(const float4*)(cls_w + c4);
  else        val = *(const float4*)(x_num + ((size_t)b*512 + (s-1))*512 + c4);
  *(float4*)(x + (size_t)row*DMODEL + c4) = val;
  ushort4 pk;
  pk.x = f2h(val.x); pk.y = f2h(val.y); pk.z = f2h(val.z); pk.w = f2h(val.w);
  *(ushort4*)(xb + (size_t)row*DMODEL + c4) = pk;
}

// ---------------------------------------------------------------------------
// ReGLU: h[n,j] = g[n,j] * relu(g[n,682+j]) for j<682; pad cols 682..703 = 0
// ---------------------------------------------------------------------------
__global__ void reglu_kernel(const ushort* __restrict__ gbuf, ushort* __restrict__ h, int nrows)
{
  const size_t i = (size_t)blockIdx.x*256 + threadIdx.x;
  if (i >= (size_t)nrows*352) return;
  const int row = (int)(i / 352);
  const int pr = (int)(i - (size_t)row*352);
  const int j = pr*2;
  ushort2 res; res.x = 0; res.y = 0;
  if (j < DHID) {
    ushort2 ga = *(const ushort2*)(gbuf + (size_t)row*DH2P + j);
    ushort2 gb = *(const ushort2*)(gbuf + (size_t)row*DH2P + DHID + j);
    res.x = f2h(h2f(ga.x) * fmaxf(h2f(gb.x), 0.f));
    res.y = f2h(h2f(ga.y) * fmaxf(h2f(gb.y), 0.f));
  }
  *(ushort2*)(h + (size_t)row*DHP + j) = res;
}

// ---------------------------------------------------------------------------
// Weight convert fp32 -> fp16 with padding. out[l][r][c] over RP x CP grid.
// ---------------------------------------------------------------------------
__global__ void convert_pad(const float* __restrict__ in, ushort* __restrict__ out,
                            int R, int C, int RP, int CP, int layers)
{
  const size_t i = (size_t)blockIdx.x*256 + threadIdx.x;
  const size_t per = (size_t)RP*CP;
  if (i >= per*layers) return;
  const int l = (int)(i / per);
  const int rem = (int)(i - (size_t)l*per);
  const int r = rem / CP;
  const int c = rem - r*CP;
  ushort val = 0;
  if (r < R && c < C) val = f2h(in[((size_t)l*R + r)*C + c]);
  out[i] = val;
}

__global__ void pad_bias(const float* __restrict__ in, float* __restrict__ out)
{
  const int i = blockIdx.x*256 + threadIdx.x;
  if (i >= 4*DH2P) return;
  const int l = i / DH2P, j = i - l*DH2P;
  out[i] = (j < DHID2) ? in[l*DHID2 + j] : 0.f;
}

// gather CLS rows: xq = fp16 LN'd CLS rows, xc = fp32 residual CLS rows
__global__ void gather_cls(const ushort* __restrict__ xb, const float* __restrict__ x,
                           ushort* __restrict__ xq, float* __restrict__ xc)
{
  const int b = blockIdx.x, lane = threadIdx.x;
  const size_t src = (size_t)b*SEQ*DMODEL;
  *(short8*)(xq + b*DMODEL + lane*8) = *(const short8*)(xb + src + lane*8);
  *(float4*)(xc + b*DMODEL + lane*8)     = *(const float4*)(x + src + lane*8);
  *(float4*)(xc + b*DMODEL + lane*8 + 4) = *(const float4*)(x + src + lane*8 + 4);
}

// ---------------------------------------------------------------------------
// Last-layer single-query attention: grid B*H, 256 threads.
// ---------------------------------------------------------------------------
__global__ __launch_bounds__(256) void attn_decode(
    const ushort* __restrict__ qc, const ushort* __restrict__ k,
    const ushort* __restrict__ v, ushort* __restrict__ oc)
{
  const int bh = blockIdx.x;
  const int b = bh >> 3, h = bh & 7;
  const int t = threadIdx.x;
  __shared__ float sc[SEQ];
  __shared__ float qsh[64];
  __shared__ float red[8];
  __shared__ float osum[256];
  if (t < 64) qsh[t] = h2f(qc[b*DMODEL + h*64 + t]) * 0.125f;
  __syncthreads();
  for (int key = t; key < SEQ; key += 256) {
    const ushort* kr = k + ((size_t)b*SEQ + key)*DMODEL + h*64;
    float s = 0.f;
#pragma unroll 8
    for (int d = 0; d < 64; ++d) s += qsh[d]*h2f(kr[d]);
    sc[key] = s;
  }
  __syncthreads();
  float lm = -1e30f;
  for (int key = t; key < SEQ; key += 256) lm = fmaxf(lm, sc[key]);
#pragma unroll
  for (int mask=1; mask<64; mask<<=1) lm = fmaxf(lm, __shfl_xor(lm, mask));
  if ((t&63)==0) red[t>>6] = lm;
  __syncthreads();
  const float mx = fmaxf(fmaxf(red[0],red[1]), fmaxf(red[2],red[3]));
  float ls = 0.f;
  for (int key = t; key < SEQ; key += 256){ float pp = __expf(sc[key]-mx); sc[key]=pp; ls += pp; }
#pragma unroll
  for (int mask=1; mask<64; mask<<=1) ls += __shfl_xor(ls, mask);
  if ((t&63)==0) red[4 + (t>>6)] = ls;
  __syncthreads();
  const float ssum = red[4]+red[5]+red[6]+red[7];
  const int d = t & 63, kc = t >> 6;
  float op = 0.f;
  for (int key = kc; key < SEQ; key += 4)
    op += sc[key] * h2f(v[((size_t)b*SEQ + key)*DMODEL + h*64 + d]);
  osum[t] = op;
  __syncthreads();
  if (t < 64) {
    const float oo = (osum[t]+osum[64+t]+osum[128+t]+osum[192+t]) / ssum;
    oc[b*DMODEL + h*64 + t] = f2h(oo);
  }
}

// final: LN -> relu -> dot(head_w) + head_b. One wave per row.
__global__ void head_kernel(const float* __restrict__ xc, const float* __restrict__ g,
                            const float* __restrict__ be, const float* __restrict__ hw,
                            const float* __restrict__ hb, float* __restrict__ out)
{
  const int row = blockIdx.x;
  const int lane = threadIdx.x;
  const float* xr = xc + (size_t)row*DMODEL;
  float4 a = *(const float4*)(xr + lane*8);
  float4 b = *(const float4*)(xr + lane*8 + 4);
  float s  = a.x+a.y+a.z+a.w+b.x+b.y+b.z+b.w;
  float ss = a.x*a.x+a.y*a.y+a.z*a.z+a.w*a.w+b.x*b.x+b.y*b.y+b.z*b.z+b.w*b.w;
#pragma unroll
  for (int mask=1; mask<64; mask<<=1){ s += __shfl_xor(s,mask); ss += __shfl_xor(ss,mask); }
  const float mu = s*(1.f/512.f);
  const float rstd = rsqrtf(ss*(1.f/512.f) - mu*mu + 1e-5f);
  float vals[8] = {a.x,a.y,a.z,a.w,b.x,b.y,b.z,b.w};
  float acc = 0.f;
#pragma unroll
  for (int j=0;j<8;++j){
    const int c = lane*8 + j;
    float tv = (vals[j]-mu)*rstd*g[c] + be[c];
    acc += fmaxf(tv, 0.f) * hw[c];
  }
#pragma unroll
  for (int mask=1; mask<64; mask<<=1) acc += __shfl_xor(acc, mask);
  if (lane==0) out[row] = acc + hb[0];
}

// ---------------------------------------------------------------------------
extern "C" void kernel_launch(void* const* d_in, const int* in_sizes, int n_in,
                              void* d_out, int out_size, void* d_ws, size_t ws_size,
                              hipStream_t stream)
{
  const float* x_num = (const float*)d_in[0];
  const float* cls_w = (const float*)d_in[1];
  const float* Wq = (const float*)d_in[2];
  const float* bq = (const float*)d_in[3];
  const float* Wk = (const float*)d_in[4];
  const float* bk = (const float*)d_in[5];
  const float* Wv = (const float*)d_in[6];
  const float* bv = (const float*)d_in[7];
  const float* Wo = (const float*)d_in[8];
  const float* bo = (const float*)d_in[9];
  const float* l0_w = (const float*)d_in[10];
  const float* l0_b = (const float*)d_in[11];
  const float* l1_w = (const float*)d_in[12];
  const float* l1_b = (const float*)d_in[13];
  const float* n0_g = (const float*)d_in[14];
  const float* n0_b = (const float*)d_in[15];
  const float* n1_g = (const float*)d_in[16];
  const float* n1_b = (const float*)d_in[17];
  const float* ln_g = (const float*)d_in[18];
  const float* ln_b = (const float*)d_in[19];
  const float* head_w = (const float*)d_in[20];
  const float* head_b = (const float*)d_in[21];
  float* out = (float*)d_out;

  char* p = (char*)d_ws;
  auto alloc = [&](size_t bytes){ char* r = p; p += (bytes + 255) & ~(size_t)255; return r; };

  float* x  = (float*)alloc((size_t)NROWS*DMODEL*4);          // 134.5 MB, residual fp32
  char* U   = alloc((size_t)NROWS*DHP*2);                     // 92.5 MB: xb / attn-out / ffn-h
  ushort* xb = (ushort*)U;
  ushort* ob = (ushort*)U;
  ushort* hb = (ushort*)U;
  char* QKVG = alloc((size_t)NROWS*DMODEL*2*3);               // 201.7 MB: q,k,v; also g (184.9 MB)
  ushort* qb = (ushort*)QKVG;
  ushort* kb = (ushort*)(QKVG + (size_t)NROWS*DMODEL*2);
  ushort* vb = (ushort*)(QKVG + (size_t)NROWS*DMODEL*2*2);
  ushort* gbuf = (ushort*)QKVG;
  ushort* wqb = (ushort*)alloc((size_t)4*512*512*2);
  ushort* wkb = (ushort*)alloc((size_t)4*512*512*2);
  ushort* wvb = (ushort*)alloc((size_t)4*512*512*2);
  ushort* wob = (ushort*)alloc((size_t)4*512*512*2);
  ushort* l0wp = (ushort*)alloc((size_t)4*DH2P*512*2);
  ushort* l1wp = (ushort*)alloc((size_t)4*512*DHP*2);
  float*  l0bp = (float*)alloc((size_t)4*DH2P*4);
  ushort* xq_cls = (ushort*)alloc(128*512*2);
  float*  xcf = (float*)alloc(128*512*4);
  ushort* qc = (ushort*)alloc(128*512*2);
  ushort* oc = (ushort*)alloc(128*512*2);
  ushort* gc = (ushort*)alloc((size_t)128*DH2P*2);
  ushort* hc = (ushort*)alloc((size_t)128*DHP*2);
  ushort* xcb = (ushort*)alloc(128*512*2);

  auto cdiv = [](size_t a, size_t b){ return (unsigned)((a + b - 1)/b); };

  // weight conversion (fp16, padded)
  convert_pad<<<cdiv((size_t)4*512*512,256),256,0,stream>>>(Wq, wqb, 512,512,512,512,4);
  convert_pad<<<cdiv((size_t)4*512*512,256),256,0,stream>>>(Wk, wkb, 512,512,512,512,4);
  convert_pad<<<cdiv((size_t)4*512*512,256),256,0,stream>>>(Wv, wvb, 512,512,512,512,4);
  convert_pad<<<cdiv((size_t)4*512*512,256),256,0,stream>>>(Wo, wob, 512,512,512,512,4);
  convert_pad<<<cdiv((size_t)4*DH2P*512,256),256,0,stream>>>(l0_w, l0wp, DHID2,512,DH2P,512,4);
  convert_pad<<<cdiv((size_t)4*512*DHP,256),256,0,stream>>>(l1_w, l1wp, 512,DHID,512,DHP,4);
  pad_bias<<<cdiv(4*DH2P,256),256,0,stream>>>(l0_b, l0bp);

  embed_kernel<<<cdiv((size_t)NROWS*128,256),256,0,stream>>>(x_num, cls_w, x, xb);

  const dim3 g512(4, 513), gl0(11, 513);
  for (int i = 0; i < 3; ++i) {
    if (i > 0)
      ln_kernel<<<cdiv(NROWS,4),256,0,stream>>>(x, n0_g+(size_t)(i-1)*512, n0_b+(size_t)(i-1)*512, xb, NROWS);
    gemm_bt<0><<<g512,256,0,stream>>>(xb, wqb+(size_t)i*262144, bq+i*512, qb, nullptr, 512, 512);
    gemm_bt<0><<<g512,256,0,stream>>>(xb, wkb+(size_t)i*262144, bk+i*512, kb, nullptr, 512, 512);
    gemm_bt<0><<<g512,256,0,stream>>>(xb, wvb+(size_t)i*262144, bv+i*512, vb, nullptr, 512, 512);
    attn_flash<<<dim3(5,8,128),256,0,stream>>>(qb, kb, vb, ob);
    gemm_bt<1><<<g512,256,0,stream>>>(ob, wob+(size_t)i*262144, bo+i*512, nullptr, x, 512, 512);
    ln_kernel<<<cdiv(NROWS,4),256,0,stream>>>(x, n1_g+(size_t)i*512, n1_b+(size_t)i*512, xb, NROWS);
    gemm_bt<0><<<gl0,256,0,stream>>>(xb, l0wp+(size_t)i*DH2P*512, l0bp+i*DH2P, gbuf, nullptr, 512, DH2P);
    reglu_kernel<<<cdiv((size_t)NROWS*352,256),256,0,stream>>>(gbuf, hb, NROWS);
    gemm_bt<1><<<g512,256,0,stream>>>(hb, l1wp+(size_t)i*512*DHP, l1_b+i*512, nullptr, x, DHP, 512);
  }

  // layer 3 (CLS query only)
  ln_kernel<<<cdiv(NROWS,4),256,0,stream>>>(x, n0_g+2*512, n0_b+2*512, xb, NROWS);
  gather_cls<<<128,64,0,stream>>>(xb, x, xq_cls, xcf);
  gemm_bt<0><<<dim3(4,1),256,0,stream>>>(xq_cls, wqb+(size_t)3*262144, bq+3*512, qc, nullptr, 512, 512);
  gemm_bt<0><<<g512,256,0,stream>>>(xb, wkb+(size_t)3*262144, bk+3*512, kb, nullptr, 512, 512);
  gemm_bt<0><<<g512,256,0,stream>>>(xb, wvb+(size_t)3*262144, bv+3*512, vb, nullptr, 512, 512);
  attn_decode<<<1024,256,0,stream>>>(qc, kb, vb, oc);
  gemm_bt<1><<<dim3(4,1),256,0,stream>>>(oc, wob+(size_t)3*262144, bo+3*512, nullptr, xcf, 512, 512);
  ln_kernel<<<cdiv(128,4),256,0,stream>>>(xcf, n1_g+3*512, n1_b+3*512, xcb, 128);
  gemm_bt<0><<<dim3(11,1),256,0,stream>>>(xcb, l0wp+(size_t)3*DH2P*512, l0bp+3*DH2P, gc, nullptr, 512, DH2P);
  reglu_kernel<<<cdiv((size_t)128*352,256),256,0,stream>>>(gc, hc, 128);
  gemm_bt<1><<<dim3(4,1),256,0,stream>>>(hc, l1wp+(size_t)3*512*DHP, l1_b+3*512, nullptr, xcf, DHP, 512);
  head_kernel<<<128,64,0,stream>>>(xcf, ln_g, ln_b, head_w, head_b, out);
}

// Round 3
// 3397.224 us; speedup vs baseline: 1.0968x; 1.0968x over previous
//
#include <hip/hip_runtime.h>
#include <stdint.h>

typedef __attribute__((ext_vector_type(4))) float f32x4;
typedef __attribute__((ext_vector_type(8))) short short8;
typedef __attribute__((ext_vector_type(8))) _Float16 half8;

#define DMODEL 512
#define SEQ 513
#define BATCH 128
#define NROWS (BATCH*SEQ)   // 65664 = 513 * 128
#define DHID 682
#define DHID2 1364
#define DH2P 1408
#define DHP 704
#define KVB 64
#define NKT 9

__device__ __forceinline__ float h2f(ushort u){ return (float)__builtin_bit_cast(_Float16, u); }
__device__ __forceinline__ ushort f2h(float f){ return __builtin_bit_cast(ushort, (_Float16)f); }
__device__ __forceinline__ f32x4 splat4(float x){ f32x4 v; v[0]=x; v[1]=x; v[2]=x; v[3]=x; return v; }
__device__ __forceinline__ f32x4 max4(f32x4 a, f32x4 b){
  f32x4 r;
#pragma unroll
  for(int i=0;i<4;i++) r[i]=fmaxf(a[i],b[i]);
  return r;
}
__device__ __forceinline__ void gload16(const void* g, void* lds){
  __builtin_amdgcn_global_load_lds((const __attribute__((address_space(1))) void*)g,
                                   (__attribute__((address_space(3))) void*)lds, 16, 0, 0);
}

// ---------------------------------------------------------------------------
// GEMM: C[N x O] = A[N x K] @ W[O x K]^T (+bias*bscale). fp16 in, fp32 accum.
// EPI=0: write fp16 C. EPI=1: Cf[idx] += acc + bias.
// m97 structure: 128x128 tile, BK=32, 4 waves, global_load_lds width 16.
// ---------------------------------------------------------------------------
template<int EPI>
__global__ __launch_bounds__(256,2) void gemm_bt(
    const ushort* __restrict__ A, const ushort* __restrict__ W,
    const float* __restrict__ bias, ushort* __restrict__ Cb, float* __restrict__ Cf,
    int K, int ldc, float bscale)
{
  __shared__ ushort As[128*32];
  __shared__ ushort Ws[128*32];
  const int t = threadIdx.x;
  const int lane = t & 63, w = t >> 6;
  const int row0 = blockIdx.y << 7, col0 = blockIdx.x << 7;
  const int wr = (w >> 1) << 6, wc = (w & 1) << 6;
  const int srow = (w << 4) + (lane >> 2);   // row within 64-row half
  const int scol = (lane & 3) << 3;          // elem offset in row
  const ushort* Ag = A + (size_t)(row0 + srow) * K + scol;
  const ushort* Wg = W + (size_t)(col0 + srow) * K + scol;
  char* AsB = (char*)As;
  char* WsB = (char*)Ws;
  const int ldsw = w << 10;

  f32x4 acc[4][4] = {};

  for (int k0 = 0; k0 < K; k0 += 32) {
    __syncthreads();
    gload16(Ag + k0,                AsB + ldsw);
    gload16(Ag + (size_t)64*K + k0, AsB + 4096 + ldsw);
    gload16(Wg + k0,                WsB + ldsw);
    gload16(Wg + (size_t)64*K + k0, WsB + 4096 + ldsw);
    __syncthreads();
    const int fr = lane & 15, fo = (lane >> 4) << 3;
    half8 af[4], wf[4];
#pragma unroll
    for (int m = 0; m < 4; ++m) af[m] = *(const half8*)&As[(wr + m*16 + fr)*32 + fo];
#pragma unroll
    for (int n = 0; n < 4; ++n) wf[n] = *(const half8*)&Ws[(wc + n*16 + fr)*32 + fo];
#pragma unroll
    for (int m = 0; m < 4; ++m)
#pragma unroll
      for (int n = 0; n < 4; ++n)
        acc[m][n] = __builtin_amdgcn_mfma_f32_16x16x32_f16(af[m], wf[n], acc[m][n], 0, 0, 0);
  }

  const int fr = lane & 15;
  const int r0 = (lane >> 4) << 2;
#pragma unroll
  for (int m = 0; m < 4; ++m) {
    const int rg = row0 + wr + m*16 + r0;
#pragma unroll
    for (int n = 0; n < 4; ++n) {
      const int cg = col0 + wc + n*16 + fr;
      const float bi = bias[cg] * bscale;
      if (EPI == 0) {
#pragma unroll
        for (int r = 0; r < 4; ++r)
          Cb[(size_t)(rg + r)*ldc + cg] = f2h(acc[m][n][r] + bi);
      } else {
#pragma unroll
        for (int r = 0; r < 4; ++r) {
          const size_t ix = (size_t)(rg + r)*ldc + cg;
          Cf[ix] += acc[m][n][r] + bi;
        }
      }
    }
  }
}

// ---------------------------------------------------------------------------
// Flash attention v2. grid (5 qtiles, 8 heads, 128 batch), 256 thr, 4 waves.
// KVB=64 keys/tile, 9 tiles. K,V double-buffered in XOR-swizzled LDS.
// addr(row, off) = row*128 + (off ^ ((row>>3 & 7)<<4)).
// Q is pre-scaled by 1/8 (folded into Wq/bq). One barrier per tile.
// ---------------------------------------------------------------------------
__global__ __launch_bounds__(256,3) void attn_flash(
    const ushort* __restrict__ q, const ushort* __restrict__ k,
    const ushort* __restrict__ v, ushort* __restrict__ o)
{
  const int qt = blockIdx.x, h = blockIdx.y, b = blockIdx.z;
  const int t = threadIdx.x, lane = t & 63, w = t >> 6;
  const size_t rowB = (size_t)b * SEQ;
  // Kb: [2][8192B]  Vb: +16384 [2][8192B]  P: +32768 [4][4608B]
  __shared__ char lds[51200];
  char* const pb = lds + 32768 + w*4608;

  const int fr = lane & 15, g = lane >> 4;
  const int qr0 = qt*128 + w*32;

  // Q fragments (scale folded into weights)
  half8 qf[2][2];
#pragma unroll
  for (int m = 0; m < 2; ++m) {
    const int qrow = qr0 + m*16 + fr;
    const bool ok = qrow < SEQ;
#pragma unroll
    for (int kk = 0; kk < 2; ++kk) {
      half8 val = {};
      if (ok) val = *(const half8*)&q[(rowB + qrow)*DMODEL + h*64 + kk*32 + g*8];
      qf[m][kk] = val;
    }
  }

  f32x4 accO[2][4] = {};
  f32x4 mrun[2], lrun[2];
  mrun[0] = splat4(-1e30f); mrun[1] = splat4(-1e30f);
  lrun[0] = splat4(0.f);    lrun[1] = splat4(0.f);

  // staging coords: 4 threads per key, 16 dims each
  const int skey = t >> 2;           // 0..63
  const int d0 = (t & 3) << 4;       // 0,16,32,48

  short8 kr0, kr1, vr0, vr1;
  auto LOADT = [&](int kt) {
    const int keyg = kt*KVB + skey;
    if (keyg < SEQ) {
      const ushort* kp = k + (rowB + keyg)*DMODEL + h*64 + d0;
      const ushort* vp = v + (rowB + keyg)*DMODEL + h*64 + d0;
      kr0 = *(const short8*)kp;  kr1 = *(const short8*)(kp + 8);
      vr0 = *(const short8*)vp;  vr1 = *(const short8*)(vp + 8);
    } else {
      kr0 = short8{}; kr1 = short8{}; vr0 = short8{}; vr1 = short8{};
    }
  };
  auto STORET = [&](int buf) {
    char* kb = lds + buf*8192;
    char* vb = lds + 16384 + buf*8192;
    const int xk = ((skey>>3)&7) << 4;
    *(short8*)(kb + skey*128 + ((2*d0)      ^ xk)) = kr0;
    *(short8*)(kb + skey*128 + ((2*d0 + 16) ^ xk)) = kr1;
#pragma unroll
    for (int j = 0; j < 16; ++j) {
      const int d = d0 + j;
      const ushort val = (ushort)(j < 8 ? vr0[j] : vr1[j-8]);
      *(ushort*)(vb + d*128 + ((2*skey) ^ (((d>>3)&7) << 4))) = val;
    }
  };

  LOADT(0);
  STORET(0);

  for (int kt = 0; kt < NKT; ++kt) {
    __syncthreads();                     // buf[kt&1] fully staged
    char* kb = lds + (kt&1)*8192;
    char* vb = lds + 16384 + (kt&1)*8192;
    if (kt+1 < NKT) LOADT(kt+1);         // async global->reg under compute

    // ---- QK^T: sc[m][n], qrow=(g*4+r)+16m, key=(16n+fr)
    f32x4 sc[2][4] = {};
#pragma unroll
    for (int kk = 0; kk < 2; ++kk) {
      half8 bf[4];
#pragma unroll
      for (int n = 0; n < 4; ++n) {
        const int row = n*16 + fr;
        bf[n] = *(const half8*)(kb + row*128 + ((kk*64 + g*16) ^ (((row>>3)&7) << 4)));
      }
#pragma unroll
      for (int m = 0; m < 2; ++m)
#pragma unroll
        for (int n = 0; n < 4; ++n)
          sc[m][n] = __builtin_amdgcn_mfma_f32_16x16x32_f16(qf[m][kk], bf[n], sc[m][n], 0, 0, 0);
    }
    if (kt == NKT-1) {
#pragma unroll
      for (int n = 0; n < 4; ++n)
        if (kt*KVB + n*16 + fr > 512) { sc[0][n] = splat4(-1e30f); sc[1][n] = splat4(-1e30f); }
    }

    // ---- online softmax per m
#pragma unroll
    for (int m = 0; m < 2; ++m) {
      f32x4 tm = max4(max4(sc[m][0], sc[m][1]), max4(sc[m][2], sc[m][3]));
#pragma unroll
      for (int mask = 1; mask <= 8; mask <<= 1) {
        f32x4 ot;
#pragma unroll
        for (int r = 0; r < 4; ++r) ot[r] = __shfl_xor(tm[r], mask);
        tm = max4(tm, ot);
      }
      const f32x4 mnew = max4(mrun[m], tm);
      f32x4 al;
#pragma unroll
      for (int r = 0; r < 4; ++r) al[r] = __expf(mrun[m][r] - mnew[r]);
      f32x4 pp[4];
#pragma unroll
      for (int n = 0; n < 4; ++n)
#pragma unroll
        for (int r = 0; r < 4; ++r) pp[n][r] = __expf(sc[m][n][r] - mnew[r]);
      f32x4 rs = (pp[0] + pp[1]) + (pp[2] + pp[3]);
#pragma unroll
      for (int mask = 1; mask <= 8; mask <<= 1) {
        f32x4 ot;
#pragma unroll
        for (int r = 0; r < 4; ++r) ot[r] = __shfl_xor(rs[r], mask);
        rs += ot;
      }
      lrun[m] = lrun[m]*al + rs;
      mrun[m] = mnew;
#pragma unroll
      for (int n2 = 0; n2 < 4; ++n2) accO[m][n2] *= al;
      // P write: row=(m*16+g*4+r) stride 144B (16B-aligned rows), col=key
#pragma unroll
      for (int n = 0; n < 4; ++n)
#pragma unroll
        for (int r = 0; r < 4; ++r)
          *(ushort*)(pb + (m*16 + g*4 + r)*144 + (n*16 + fr)*2) = f2h(pp[n][r]);
    }

    asm volatile("" ::: "memory");   // keep P writes before PV reads

    // ---- PV: accO[m][dn] += P[qrow][key] * V[key][d]
#pragma unroll
    for (int kk2 = 0; kk2 < 2; ++kk2) {
      half8 pf[2];
#pragma unroll
      for (int m = 0; m < 2; ++m)
        pf[m] = *(const half8*)(pb + (m*16 + fr)*144 + kk2*64 + g*16);
      half8 vf[4];
#pragma unroll
      for (int dn = 0; dn < 4; ++dn) {
        const int row = dn*16 + fr;
        vf[dn] = *(const half8*)(vb + row*128 + ((kk2*64 + g*16) ^ (((row>>3)&7) << 4)));
      }
#pragma unroll
      for (int m = 0; m < 2; ++m)
#pragma unroll
        for (int dn = 0; dn < 4; ++dn)
          accO[m][dn] = __builtin_amdgcn_mfma_f32_16x16x32_f16(pf[m], vf[dn], accO[m][dn], 0, 0, 0);
    }

    if (kt+1 < NKT) STORET((kt+1)&1);  // other buffer; no barrier needed here
  }

#pragma unroll
  for (int m = 0; m < 2; ++m)
#pragma unroll
    for (int r = 0; r < 4; ++r) {
      const int qrow = qr0 + m*16 + g*4 + r;
      if (qrow < SEQ) {
        const float inv = 1.f / lrun[m][r];
#pragma unroll
        for (int dn = 0; dn < 4; ++dn)
          o[(rowB + qrow)*DMODEL + h*64 + dn*16 + fr] = f2h(accO[m][dn][r] * inv);
      }
    }
}

// ---------------------------------------------------------------------------
// LayerNorm fp32 -> fp16. One wave per row (D=512, 8 elems/lane).
// ---------------------------------------------------------------------------
__global__ __launch_bounds__(256) void ln_kernel(
    const float* __restrict__ x, const float* __restrict__ gamma, const float* __restrict__ beta,
    ushort* __restrict__ out, int nrows)
{
  const int row = blockIdx.x*4 + (threadIdx.x >> 6);
  const int lane = threadIdx.x & 63;
  if (row >= nrows) return;
  const float* xr = x + (size_t)row*DMODEL;
  float4 a = *(const float4*)(xr + lane*8);
  float4 b = *(const float4*)(xr + lane*8 + 4);
  float s  = a.x+a.y+a.z+a.w+b.x+b.y+b.z+b.w;
  float ss = a.x*a.x+a.y*a.y+a.z*a.z+a.w*a.w+b.x*b.x+b.y*b.y+b.z*b.z+b.w*b.w;
#pragma unroll
  for (int mask=1; mask<64; mask<<=1){ s += __shfl_xor(s,mask); ss += __shfl_xor(ss,mask); }
  const float mu = s*(1.f/512.f);
  const float rstd = rsqrtf(ss*(1.f/512.f) - mu*mu + 1e-5f);
  float vals[8] = {a.x,a.y,a.z,a.w,b.x,b.y,b.z,b.w};
  short8 pk;
#pragma unroll
  for (int j=0;j<8;++j){
    const int c = lane*8 + j;
    pk[j] = (short)f2h((vals[j]-mu)*rstd*gamma[c] + beta[c]);
  }
  *(short8*)(out + (size_t)row*DMODEL + lane*8) = pk;
}

// ---------------------------------------------------------------------------
// Embed: x[b,0,:]=cls, x[b,1+t,:]=x_num[b,t,:]; also xb = fp16(x)
// ---------------------------------------------------------------------------
__global__ void embed_kernel(const float* __restrict__ x_num, const float* __restrict__ cls_w,
                             float* __restrict__ x, ushort* __restrict__ xb)
{
  const size_t i = (size_t)blockIdx.x*256 + threadIdx.x;
  if (i >= (size_t)NROWS*128) return;
  const int row = (int)(i >> 7);
  const int c4 = ((int)(i & 127)) << 2;
  const int b = row / SEQ;
  const int s = row - b*SEQ;
  float4 val;
  if (s == 0) val = *(const float4*)(cls_w + c4);
  else        val = *(const float4*)(x_num + ((size_t)b*512 + (s-1))*512 + c4);
  *(float4*)(x + (size_t)row*DMODEL + c4) = val;
  ushort4 pk;
  pk.x = f2h(val.x); pk.y = f2h(val.y); pk.z = f2h(val.z); pk.w = f2h(val.w);
  *(ushort4*)(xb + (size_t)row*DMODEL + c4) = pk;
}

// ---------------------------------------------------------------------------
// ReGLU: h[n,j] = g[n,j] * relu(g[n,682+j]) for j<682; pad cols 682..703 = 0
// ---------------------------------------------------------------------------
__global__ void reglu_kernel(const ushort* __restrict__ gbuf, ushort* __restrict__ h, int nrows)
{
  const size_t i = (size_t)blockIdx.x*256 + threadIdx.x;
  if (i >= (size_t)nrows*352) return;
  const int row = (int)(i / 352);
  const int pr = (int)(i - (size_t)row*352);
  const int j = pr*2;
  ushort2 res; res.x = 0; res.y = 0;
  if (j < DHID) {
    ushort2 ga = *(const ushort2*)(gbuf + (size_t)row*DH2P + j);
    ushort2 gb = *(const ushort2*)(gbuf + (size_t)row*DH2P + DHID + j);
    res.x = f2h(h2f(ga.x) * fmaxf(h2f(gb.x), 0.f));
    res.y = f2h(h2f(ga.y) * fmaxf(h2f(gb.y), 0.f));
  }
  *(ushort2*)(h + (size_t)row*DHP + j) = res;
}

// ---------------------------------------------------------------------------
// Weight convert fp32 -> fp16 (×scale) with padding.
// ---------------------------------------------------------------------------
__global__ void convert_pad(const float* __restrict__ in, ushort* __restrict__ out,
                            int R, int C, int RP, int CP, int layers, float scale)
{
  const size_t i = (size_t)blockIdx.x*256 + threadIdx.x;
  const size_t per = (size_t)RP*CP;
  if (i >= per*layers) return;
  const int l = (int)(i / per);
  const int rem = (int)(i - (size_t)l*per);
  const int r = rem / CP;
  const int c = rem - r*CP;
  ushort val = 0;
  if (r < R && c < C) val = f2h(in[((size_t)l*R + r)*C + c] * scale);
  out[i] = val;
}

__global__ void pad_bias(const float* __restrict__ in, float* __restrict__ out)
{
  const int i = blockIdx.x*256 + threadIdx.x;
  if (i >= 4*DH2P) return;
  const int l = i / DH2P, j = i - l*DH2P;
  out[i] = (j < DHID2) ? in[l*DHID2 + j] : 0.f;
}

// gather CLS rows: xq = fp16 LN'd CLS rows, xc = fp32 residual CLS rows
__global__ void gather_cls(const ushort* __restrict__ xb, const float* __restrict__ x,
                           ushort* __restrict__ xq, float* __restrict__ xc)
{
  const int b = blockIdx.x, lane = threadIdx.x;
  const size_t src = (size_t)b*SEQ*DMODEL;
  *(short8*)(xq + b*DMODEL + lane*8) = *(const short8*)(xb + src + lane*8);
  *(float4*)(xc + b*DMODEL + lane*8)     = *(const float4*)(x + src + lane*8);
  *(float4*)(xc + b*DMODEL + lane*8 + 4) = *(const float4*)(x + src + lane*8 + 4);
}

// ---------------------------------------------------------------------------
// Last-layer single-query attention: grid B*H, 256 threads. q pre-scaled.
// ---------------------------------------------------------------------------
__global__ __launch_bounds__(256) void attn_decode(
    const ushort* __restrict__ qc, const ushort* __restrict__ k,
    const ushort* __restrict__ v, ushort* __restrict__ oc)
{
  const int bh = blockIdx.x;
  const int b = bh >> 3, h = bh & 7;
  const int t = threadIdx.x;
  __shared__ float sc[SEQ];
  __shared__ float qsh[64];
  __shared__ float red[8];
  __shared__ float osum[256];
  if (t < 64) qsh[t] = h2f(qc[b*DMODEL + h*64 + t]);
  __syncthreads();
  for (int key = t; key < SEQ; key += 256) {
    const ushort* kr = k + ((size_t)b*SEQ + key)*DMODEL + h*64;
    float s = 0.f;
#pragma unroll 8
    for (int d = 0; d < 64; ++d) s += qsh[d]*h2f(kr[d]);
    sc[key] = s;
  }
  __syncthreads();
  float lm = -1e30f;
  for (int key = t; key < SEQ; key += 256) lm = fmaxf(lm, sc[key]);
#pragma unroll
  for (int mask=1; mask<64; mask<<=1) lm = fmaxf(lm, __shfl_xor(lm, mask));
  if ((t&63)==0) red[t>>6] = lm;
  __syncthreads();
  const float mx = fmaxf(fmaxf(red[0],red[1]), fmaxf(red[2],red[3]));
  float ls = 0.f;
  for (int key = t; key < SEQ; key += 256){ float pp = __expf(sc[key]-mx); sc[key]=pp; ls += pp; }
#pragma unroll
  for (int mask=1; mask<64; mask<<=1) ls += __shfl_xor(ls, mask);
  if ((t&63)==0) red[4 + (t>>6)] = ls;
  __syncthreads();
  const float ssum = red[4]+red[5]+red[6]+red[7];
  const int d = t & 63, kc = t >> 6;
  float op = 0.f;
  for (int key = kc; key < SEQ; key += 4)
    op += sc[key] * h2f(v[((size_t)b*SEQ + key)*DMODEL + h*64 + d]);
  osum[t] = op;
  __syncthreads();
  if (t < 64) {
    const float oo = (osum[t]+osum[64+t]+osum[128+t]+osum[192+t]) / ssum;
    oc[b*DMODEL + h*64 + t] = f2h(oo);
  }
}

// final: LN -> relu -> dot(head_w) + head_b. One wave per row.
__global__ void head_kernel(const float* __restrict__ xc, const float* __restrict__ g,
                            const float* __restrict__ be, const float* __restrict__ hw,
                            const float* __restrict__ hb, float* __restrict__ out)
{
  const int row = blockIdx.x;
  const int lane = threadIdx.x;
  const float* xr = xc + (size_t)row*DMODEL;
  float4 a = *(const float4*)(xr + lane*8);
  float4 b = *(const float4*)(xr + lane*8 + 4);
  float s  = a.x+a.y+a.z+a.w+b.x+b.y+b.z+b.w;
  float ss = a.x*a.x+a.y*a.y+a.z*a.z+a.w*a.w+b.x*b.x+b.y*b.y+b.z*b.z+b.w*b.w;
#pragma unroll
  for (int mask=1; mask<64; mask<<=1){ s += __shfl_xor(s,mask); ss += __shfl_xor(ss,mask); }
  const float mu = s*(1.f/512.f);
  const float rstd = rsqrtf(ss*(1.f/512.f) - mu*mu + 1e-5f);
  float vals[8] = {a.x,a.y,a.z,a.w,b.x,b.y,b.z,b.w};
  float acc = 0.f;
#pragma unroll
  for (int j=0;j<8;++j){
    const int c = lane*8 + j;
    float tv = (vals[j]-mu)*rstd*g[c] + be[c];
    acc += fmaxf(tv, 0.f) * hw[c];
  }
#pragma unroll
  for (int mask=1; mask<64; mask<<=1) acc += __shfl_xor(acc, mask);
  if (lane==0) out[row] = acc + hb[0];
}

// ---------------------------------------------------------------------------
extern "C" void kernel_launch(void* const* d_in, const int* in_sizes, int n_in,
                              void* d_out, int out_size, void* d_ws, size_t ws_size,
                              hipStream_t stream)
{
  const float* x_num = (const float*)d_in[0];
  const float* cls_w = (const float*)d_in[1];
  const float* Wq = (const float*)d_in[2];
  const float* bq = (const float*)d_in[3];
  const float* Wk = (const float*)d_in[4];
  const float* bk = (const float*)d_in[5];
  const float* Wv = (const float*)d_in[6];
  const float* bv = (const float*)d_in[7];
  const float* Wo = (const float*)d_in[8];
  const float* bo = (const float*)d_in[9];
  const float* l0_w = (const float*)d_in[10];
  const float* l0_b = (const float*)d_in[11];
  const float* l1_w = (const float*)d_in[12];
  const float* l1_b = (const float*)d_in[13];
  const float* n0_g = (const float*)d_in[14];
  const float* n0_b = (const float*)d_in[15];
  const float* n1_g = (const float*)d_in[16];
  const float* n1_b = (const float*)d_in[17];
  const float* ln_g = (const float*)d_in[18];
  const float* ln_b = (const float*)d_in[19];
  const float* head_w = (const float*)d_in[20];
  const float* head_b = (const float*)d_in[21];
  float* out = (float*)d_out;

  char* p = (char*)d_ws;
  auto alloc = [&](size_t bytes){ char* r = p; p += (bytes + 255) & ~(size_t)255; return r; };

  float* x  = (float*)alloc((size_t)NROWS*DMODEL*4);          // residual fp32
  char* U   = alloc((size_t)NROWS*DHP*2);                     // xb / attn-out / ffn-h
  ushort* xb = (ushort*)U;
  ushort* ob = (ushort*)U;
  ushort* hb = (ushort*)U;
  char* QKVG = alloc((size_t)NROWS*DMODEL*2*3);               // q,k,v; also g
  ushort* qb = (ushort*)QKVG;
  ushort* kb = (ushort*)(QKVG + (size_t)NROWS*DMODEL*2);
  ushort* vb = (ushort*)(QKVG + (size_t)NROWS*DMODEL*2*2);
  ushort* gbuf = (ushort*)QKVG;
  ushort* wqb = (ushort*)alloc((size_t)4*512*512*2);
  ushort* wkb = (ushort*)alloc((size_t)4*512*512*2);
  ushort* wvb = (ushort*)alloc((size_t)4*512*512*2);
  ushort* wob = (ushort*)alloc((size_t)4*512*512*2);
  ushort* l0wp = (ushort*)alloc((size_t)4*DH2P*512*2);
  ushort* l1wp = (ushort*)alloc((size_t)4*512*DHP*2);
  float*  l0bp = (float*)alloc((size_t)4*DH2P*4);
  ushort* xq_cls = (ushort*)alloc(128*512*2);
  float*  xcf = (float*)alloc(128*512*4);
  ushort* qc = (ushort*)alloc(128*512*2);
  ushort* oc = (ushort*)alloc(128*512*2);
  ushort* gc = (ushort*)alloc((size_t)128*DH2P*2);
  ushort* hc = (ushort*)alloc((size_t)128*DHP*2);
  ushort* xcb = (ushort*)alloc(128*512*2);

  auto cdiv = [](size_t a, size_t b){ return (unsigned)((a + b - 1)/b); };

  // weight conversion (fp16, padded; Wq scaled by 1/8 = 1/sqrt(dh))
  convert_pad<<<cdiv((size_t)4*512*512,256),256,0,stream>>>(Wq, wqb, 512,512,512,512,4, 0.125f);
  convert_pad<<<cdiv((size_t)4*512*512,256),256,0,stream>>>(Wk, wkb, 512,512,512,512,4, 1.f);
  convert_pad<<<cdiv((size_t)4*512*512,256),256,0,stream>>>(Wv, wvb, 512,512,512,512,4, 1.f);
  convert_pad<<<cdiv((size_t)4*512*512,256),256,0,stream>>>(Wo, wob, 512,512,512,512,4, 1.f);
  convert_pad<<<cdiv((size_t)4*DH2P*512,256),256,0,stream>>>(l0_w, l0wp, DHID2,512,DH2P,512,4, 1.f);
  convert_pad<<<cdiv((size_t)4*512*DHP,256),256,0,stream>>>(l1_w, l1wp, 512,DHID,512,DHP,4, 1.f);
  pad_bias<<<cdiv(4*DH2P,256),256,0,stream>>>(l0_b, l0bp);

  embed_kernel<<<cdiv((size_t)NROWS*128,256),256,0,stream>>>(x_num, cls_w, x, xb);

  const dim3 g512(4, 513), gl0(11, 513);
  for (int i = 0; i < 3; ++i) {
    if (i > 0)
      ln_kernel<<<cdiv(NROWS,4),256,0,stream>>>(x, n0_g+(size_t)(i-1)*512, n0_b+(size_t)(i-1)*512, xb, NROWS);
    gemm_bt<0><<<g512,256,0,stream>>>(xb, wqb+(size_t)i*262144, bq+i*512, qb, nullptr, 512, 512, 0.125f);
    gemm_bt<0><<<g512,256,0,stream>>>(xb, wkb+(size_t)i*262144, bk+i*512, kb, nullptr, 512, 512, 1.f);
    gemm_bt<0><<<g512,256,0,stream>>>(xb, wvb+(size_t)i*262144, bv+i*512, vb, nullptr, 512, 512, 1.f);
    attn_flash<<<dim3(5,8,128),256,0,stream>>>(qb, kb, vb, ob);
    gemm_bt<1><<<g512,256,0,stream>>>(ob, wob+(size_t)i*262144, bo+i*512, nullptr, x, 512, 512, 1.f);
    ln_kernel<<<cdiv(NROWS,4),256,0,stream>>>(x, n1_g+(size_t)i*512, n1_b+(size_t)i*512, xb, NROWS);
    gemm_bt<0><<<gl0,256,0,stream>>>(xb, l0wp+(size_t)i*DH2P*512, l0bp+i*DH2P, gbuf, nullptr, 512, DH2P, 1.f);
    reglu_kernel<<<cdiv((size_t)NROWS*352,256),256,0,stream>>>(gbuf, hb, NROWS);
    gemm_bt<1><<<g512,256,0,stream>>>(hb, l1wp+(size_t)i*512*DHP, l1_b+i*512, nullptr, x, DHP, 512, 1.f);
  }

  // layer 3 (CLS query only)
  ln_kernel<<<cdiv(NROWS,4),256,0,stream>>>(x, n0_g+2*512, n0_b+2*512, xb, NROWS);
  gather_cls<<<128,64,0,stream>>>(xb, x, xq_cls, xcf);
  gemm_bt<0><<<dim3(4,1),256,0,stream>>>(xq_cls, wqb+(size_t)3*262144, bq+3*512, qc, nullptr, 512, 512, 0.125f);
  gemm_bt<0><<<g512,256,0,stream>>>(xb, wkb+(size_t)3*262144, bk+3*512, kb, nullptr, 512, 512, 1.f);
  gemm_bt<0><<<g512,256,0,stream>>>(xb, wvb+(size_t)3*262144, bv+3*512, vb, nullptr, 512, 512, 1.f);
  attn_decode<<<1024,256,0,stream>>>(qc, kb, vb, oc);
  gemm_bt<1><<<dim3(4,1),256,0,stream>>>(oc, wob+(size_t)3*262144, bo+3*512, nullptr, xcf, 512, 512, 1.f);
  ln_kernel<<<cdiv(128,4),256,0,stream>>>(xcf, n1_g+3*512, n1_b+3*512, xcb, 128);
  gemm_bt<0><<<dim3(11,1),256,0,stream>>>(xcb, l0wp+(size_t)3*DH2P*512, l0bp+3*DH2P, gc, nullptr, 512, DH2P, 1.f);
  reglu_kernel<<<cdiv((size_t)128*352,256),256,0,stream>>>(gc, hc, 128);
  gemm_bt<1><<<dim3(4,1),256,0,stream>>>(hc, l1wp+(size_t)3*512*DHP, l1_b+3*512, nullptr, xcf, DHP, 512, 1.f);
  head_kernel<<<128,64,0,stream>>>(xcf, ln_g, ln_b, head_w, head_b, out);
}

// Round 4
// 3181.729 us; speedup vs baseline: 1.1711x; 1.0677x over previous
//
#include <hip/hip_runtime.h>
#include <stdint.h>

typedef __attribute__((ext_vector_type(4))) float f32x4;
typedef __attribute__((ext_vector_type(8))) short short8;
typedef __attribute__((ext_vector_type(8))) _Float16 half8;

#define DMODEL 512
#define SEQ 513
#define BATCH 128
#define NROWS (BATCH*SEQ)   // 65664 = 513 * 128
#define DHID 682
#define DHID2 1364
#define DH2P 1408
#define DHP 704
#define KVB 64
#define NKT 9

__device__ __forceinline__ float h2f(ushort u){ return (float)__builtin_bit_cast(_Float16, u); }
__device__ __forceinline__ ushort f2h(float f){ return __builtin_bit_cast(ushort, (_Float16)f); }
__device__ __forceinline__ f32x4 splat4(float x){ f32x4 v; v[0]=x; v[1]=x; v[2]=x; v[3]=x; return v; }
__device__ __forceinline__ void gload16(const void* g, void* lds){
  __builtin_amdgcn_global_load_lds((const __attribute__((address_space(1))) void*)g,
                                   (__attribute__((address_space(3))) void*)lds, 16, 0, 0);
}

// ---------------------------------------------------------------------------
// GEMM: C[N x O] = A[N x K] @ W[O x K]^T (+bias*bscale). fp16 in, fp32 accum.
// EPI=0: write fp16 C. EPI=1: Cf[idx] += acc + bias.
// m97 structure: 128x128 tile, BK=32, 4 waves, global_load_lds width 16.
// ---------------------------------------------------------------------------
template<int EPI>
__global__ __launch_bounds__(256,2) void gemm_bt(
    const ushort* __restrict__ A, const ushort* __restrict__ W,
    const float* __restrict__ bias, ushort* __restrict__ Cb, float* __restrict__ Cf,
    int K, int ldc, float bscale)
{
  __shared__ ushort As[128*32];
  __shared__ ushort Ws[128*32];
  const int t = threadIdx.x;
  const int lane = t & 63, w = t >> 6;
  const int row0 = blockIdx.y << 7, col0 = blockIdx.x << 7;
  const int wr = (w >> 1) << 6, wc = (w & 1) << 6;
  const int srow = (w << 4) + (lane >> 2);   // row within 64-row half
  const int scol = (lane & 3) << 3;          // elem offset in row
  const ushort* Ag = A + (size_t)(row0 + srow) * K + scol;
  const ushort* Wg = W + (size_t)(col0 + srow) * K + scol;
  char* AsB = (char*)As;
  char* WsB = (char*)Ws;
  const int ldsw = w << 10;

  f32x4 acc[4][4] = {};

  for (int k0 = 0; k0 < K; k0 += 32) {
    __syncthreads();
    gload16(Ag + k0,                AsB + ldsw);
    gload16(Ag + (size_t)64*K + k0, AsB + 4096 + ldsw);
    gload16(Wg + k0,                WsB + ldsw);
    gload16(Wg + (size_t)64*K + k0, WsB + 4096 + ldsw);
    __syncthreads();
    const int fr = lane & 15, fo = (lane >> 4) << 3;
    half8 af[4], wf[4];
#pragma unroll
    for (int m = 0; m < 4; ++m) af[m] = *(const half8*)&As[(wr + m*16 + fr)*32 + fo];
#pragma unroll
    for (int n = 0; n < 4; ++n) wf[n] = *(const half8*)&Ws[(wc + n*16 + fr)*32 + fo];
#pragma unroll
    for (int m = 0; m < 4; ++m)
#pragma unroll
      for (int n = 0; n < 4; ++n)
        acc[m][n] = __builtin_amdgcn_mfma_f32_16x16x32_f16(af[m], wf[n], acc[m][n], 0, 0, 0);
  }

  const int fr = lane & 15;
  const int r0 = (lane >> 4) << 2;
#pragma unroll
  for (int m = 0; m < 4; ++m) {
    const int rg = row0 + wr + m*16 + r0;
#pragma unroll
    for (int n = 0; n < 4; ++n) {
      const int cg = col0 + wc + n*16 + fr;
      const float bi = bias[cg] * bscale;
      if (EPI == 0) {
#pragma unroll
        for (int r = 0; r < 4; ++r)
          Cb[(size_t)(rg + r)*ldc + cg] = f2h(acc[m][n][r] + bi);
      } else {
#pragma unroll
        for (int r = 0; r < 4; ++r) {
          const size_t ix = (size_t)(rg + r)*ldc + cg;
          Cf[ix] += acc[m][n][r] + bi;
        }
      }
    }
  }
}

// ---------------------------------------------------------------------------
// Flash attention v3: swapped QK^T (scores C[key][q]), global_load_lds staging
// with source-side chunk swizzle, in-LDS V transpose, packed b64 P stores.
// Grid: 5120 flat (XCD-chunked swizzle). 4 waves, 40KB LDS, 4 blocks/CU.
// LDS swizzle convention: 16B cell (row, slot) holds global chunk slot^(row&7);
// reads use byte_off = row*128 + (off ^ ((row&7)<<4)).
// ---------------------------------------------------------------------------
__global__ __launch_bounds__(256,4) void attn_flash(
    const ushort* __restrict__ q, const ushort* __restrict__ k,
    const ushort* __restrict__ v, ushort* __restrict__ o)
{
  const int bid = blockIdx.x;
  const int sw = (bid & 7)*640 + (bid >> 3);   // bijective: 5120 % 8 == 0
  const int qt = sw % 5;
  const int hb = sw / 5;                       // b*8 + h
  const int h = hb & 7, b = hb >> 3;
  const int t = threadIdx.x, lane = t & 63, w = t >> 6;
  const int fr = lane & 15, g = lane >> 4, gq4 = g << 2;
  const size_t rowB = (size_t)b * SEQ;

  __shared__ char lds[40960];
  char* const Ks  = lds;            // [64 key][128B], swizzled
  char* const Vs  = lds + 8192;     // [64 key][128B], swizzled
  char* const VTs = lds + 16384;    // [64 d][128B keys], swizzled
  char* const pb  = lds + 24576 + w*4096;  // per-wave P [32 q][128B keys], swizzled

  const int qr0 = qt*128 + w*32;

  // Q fragments (B-operand: col=q=fr, k=d). Scale folded into Wq/bq.
  half8 qf[2][2];
#pragma unroll
  for (int nq = 0; nq < 2; ++nq) {
    const int qrow = qr0 + nq*16 + fr;
    const bool ok = qrow < SEQ;
#pragma unroll
    for (int kk = 0; kk < 2; ++kk) {
      half8 val = {};
      if (ok) val = *(const half8*)&q[(rowB + qrow)*DMODEL + h*64 + kk*32 + g*8];
      qf[nq][kk] = val;
    }
  }

  f32x4 accO[2][4] = {};
  float mrun[2] = {-1e30f, -1e30f};
  float lrun[2] = {0.f, 0.f};

  // staging: chunk = (l&7)^(l>>3); row = i*32 + w*8 + (l>>3)
  const int l8 = lane >> 3, l7 = lane & 7;
  const int chunk = l7 ^ l8;
  auto STAGE = [&](int kt2) {
#pragma unroll
    for (int i = 0; i < 2; ++i) {
      const int row = i*32 + (w<<3) + l8;
      const int keyg = min(kt2*KVB + row, 512);
      const size_t gsrc = (rowB + keyg)*DMODEL + h*64 + chunk*8;
      gload16(k + gsrc, Ks + i*4096 + w*1024);
      gload16(v + gsrc, Vs + i*4096 + w*1024);
    }
  };

  // transpose thread mapping: 4x4 cell (d0 = db*4, key0 = kb*4), 4-way banks
  const int db  = (lane & 7) | ((w & 1) << 3);
  const int kbq = l8 | ((w & 2) << 2);
  const int d0 = db << 2, key0 = kbq << 2;

  STAGE(0);

  for (int kt = 0; kt < NKT; ++kt) {
    __syncthreads();   // staged K/V ready (vmcnt(0) auto); prev PV done

    // ---- QK^T swapped: sc[mk][nq], key = mk*16 + gq4 + r, q = nq*16 + fr
    f32x4 sc[4][2] = {};
#pragma unroll
    for (int kk = 0; kk < 2; ++kk) {
      half8 kf[4];
#pragma unroll
      for (int mk = 0; mk < 4; ++mk) {
        const int row = mk*16 + fr;
        kf[mk] = *(const half8*)(Ks + row*128 + ((kk*64 + g*16) ^ ((fr&7)<<4)));
      }
#pragma unroll
      for (int mk = 0; mk < 4; ++mk)
#pragma unroll
        for (int nq = 0; nq < 2; ++nq)
          sc[mk][nq] = __builtin_amdgcn_mfma_f32_16x16x32_f16(kf[mk], qf[nq][kk], sc[mk][nq], 0, 0, 0);
    }

    // ---- in-LDS V transpose: Vs[key][d] -> VTs[d][key] (4x4 u16 per thread)
    {
      uint2 a[4];
#pragma unroll
      for (int i = 0; i < 4; ++i) {
        const int row = key0 + i;
        a[i] = *(const uint2*)(Vs + row*128 + ((d0*2) ^ ((row&7)<<4)));
      }
      uint2 bb[4];
      bb[0].x = (a[0].x & 0xffffu) | (a[1].x << 16);
      bb[0].y = (a[2].x & 0xffffu) | (a[3].x << 16);
      bb[1].x = (a[0].x >> 16) | (a[1].x & 0xffff0000u);
      bb[1].y = (a[2].x >> 16) | (a[3].x & 0xffff0000u);
      bb[2].x = (a[0].y & 0xffffu) | (a[1].y << 16);
      bb[2].y = (a[2].y & 0xffffu) | (a[3].y << 16);
      bb[3].x = (a[0].y >> 16) | (a[1].y & 0xffff0000u);
      bb[3].y = (a[2].y >> 16) | (a[3].y & 0xffff0000u);
#pragma unroll
      for (int j = 0; j < 4; ++j) {
        const int drow = d0 + j;
        *(uint2*)(VTs + drow*128 + ((key0*2) ^ ((drow&7)<<4))) = bb[j];
      }
    }

    // ---- mask last tile (only global key 512 valid -> local key 0)
    if (kt == NKT-1) {
#pragma unroll
      for (int mk = 0; mk < 4; ++mk)
#pragma unroll
        for (int r = 0; r < 4; ++r)
          if (mk + gq4 + r) { sc[mk][0][r] = -1e30f; sc[mk][1][r] = -1e30f; }
    }

    __syncthreads();   // VTs ready; all K/V reads done -> safe to restage

    if (kt+1 < NKT) STAGE(kt+1);   // in flight under softmax + PV

    // ---- online softmax (per-lane scalar m/l; q = nq*16 + fr)
    float al2[2];
#pragma unroll
    for (int nq = 0; nq < 2; ++nq) {
      float tm = sc[0][nq][0];
#pragma unroll
      for (int mk = 0; mk < 4; ++mk)
#pragma unroll
        for (int r = 0; r < 4; ++r) tm = fmaxf(tm, sc[mk][nq][r]);
      tm = fmaxf(tm, __shfl_xor(tm, 16));
      tm = fmaxf(tm, __shfl_xor(tm, 32));
      const float mnew = fmaxf(mrun[nq], tm);
      const float al = __expf(mrun[nq] - mnew);
      mrun[nq] = mnew;
      float rs = 0.f;
#pragma unroll
      for (int mk = 0; mk < 4; ++mk)
#pragma unroll
        for (int r = 0; r < 4; ++r) {
          const float pv = __expf(sc[mk][nq][r] - mnew);
          sc[mk][nq][r] = pv;
          rs += pv;
        }
      rs += __shfl_xor(rs, 16);
      rs += __shfl_xor(rs, 32);
      lrun[nq] = lrun[nq]*al + rs;
      al2[nq] = al;
      // P store: row q, keys mk*16+gq4+{0..3} packed as b64
      char* prow = pb + (nq*16 + fr)*128;
#pragma unroll
      for (int mk = 0; mk < 4; ++mk) {
        uint2 pk;
        pk.x = (uint)f2h(sc[mk][nq][0]) | ((uint)f2h(sc[mk][nq][1]) << 16);
        pk.y = (uint)f2h(sc[mk][nq][2]) | ((uint)f2h(sc[mk][nq][3]) << 16);
        *(uint2*)(prow + ((mk*32 + gq4*2) ^ ((fr&7)<<4))) = pk;
      }
    }

    // rescale accO (rows q = mq*16 + gq4 + r): fetch al from lane fr==gq4+r
#pragma unroll
    for (int mq = 0; mq < 2; ++mq)
#pragma unroll
      for (int r = 0; r < 4; ++r) {
        const float alr = __shfl(al2[mq], (lane & 48) | (gq4 + r));
#pragma unroll
        for (int dn = 0; dn < 4; ++dn) accO[mq][dn][r] *= alr;
      }

    asm volatile("" ::: "memory");   // P writes before P reads

    // ---- PV: accO[mq][dn] += P[q][key] * V^T[d][key]
#pragma unroll
    for (int kk2 = 0; kk2 < 2; ++kk2) {
      half8 pf[2];
#pragma unroll
      for (int mq = 0; mq < 2; ++mq)
        pf[mq] = *(const half8*)(pb + (mq*16 + fr)*128 + ((kk2*64 + g*16) ^ ((fr&7)<<4)));
      half8 vf[4];
#pragma unroll
      for (int dn = 0; dn < 4; ++dn) {
        const int row = dn*16 + fr;
        vf[dn] = *(const half8*)(VTs + row*128 + ((kk2*64 + g*16) ^ ((fr&7)<<4)));
      }
#pragma unroll
      for (int mq = 0; mq < 2; ++mq)
#pragma unroll
        for (int dn = 0; dn < 4; ++dn)
          accO[mq][dn] = __builtin_amdgcn_mfma_f32_16x16x32_f16(pf[mq], vf[dn], accO[mq][dn], 0, 0, 0);
    }
  }

  // epilogue: O rows q = mq*16 + gq4 + r, cols d = dn*16 + fr
#pragma unroll
  for (int mq = 0; mq < 2; ++mq)
#pragma unroll
    for (int r = 0; r < 4; ++r) {
      const int qrow = qr0 + mq*16 + gq4 + r;
      const float ls = __shfl(lrun[mq], (lane & 48) | (gq4 + r));
      if (qrow < SEQ) {
        const float inv = 1.f / ls;
#pragma unroll
        for (int dn = 0; dn < 4; ++dn)
          o[(rowB + qrow)*DMODEL + h*64 + dn*16 + fr] = f2h(accO[mq][dn][r] * inv);
      }
    }
}

// ---------------------------------------------------------------------------
// LayerNorm fp32 -> fp16. One wave per row (D=512, 8 elems/lane).
// ---------------------------------------------------------------------------
__global__ __launch_bounds__(256) void ln_kernel(
    const float* __restrict__ x, const float* __restrict__ gamma, const float* __restrict__ beta,
    ushort* __restrict__ out, int nrows)
{
  const int row = blockIdx.x*4 + (threadIdx.x >> 6);
  const int lane = threadIdx.x & 63;
  if (row >= nrows) return;
  const float* xr = x + (size_t)row*DMODEL;
  float4 a = *(const float4*)(xr + lane*8);
  float4 b = *(const float4*)(xr + lane*8 + 4);
  float s  = a.x+a.y+a.z+a.w+b.x+b.y+b.z+b.w;
  float ss = a.x*a.x+a.y*a.y+a.z*a.z+a.w*a.w+b.x*b.x+b.y*b.y+b.z*b.z+b.w*b.w;
#pragma unroll
  for (int mask=1; mask<64; mask<<=1){ s += __shfl_xor(s,mask); ss += __shfl_xor(ss,mask); }
  const float mu = s*(1.f/512.f);
  const float rstd = rsqrtf(ss*(1.f/512.f) - mu*mu + 1e-5f);
  float vals[8] = {a.x,a.y,a.z,a.w,b.x,b.y,b.z,b.w};
  short8 pk;
#pragma unroll
  for (int j=0;j<8;++j){
    const int c = lane*8 + j;
    pk[j] = (short)f2h((vals[j]-mu)*rstd*gamma[c] + beta[c]);
  }
  *(short8*)(out + (size_t)row*DMODEL + lane*8) = pk;
}

// ---------------------------------------------------------------------------
// Embed: x[b,0,:]=cls, x[b,1+t,:]=x_num[b,t,:]; also xb = fp16(x)
// ---------------------------------------------------------------------------
__global__ void embed_kernel(const float* __restrict__ x_num, const float* __restrict__ cls_w,
                             float* __restrict__ x, ushort* __restrict__ xb)
{
  const size_t i = (size_t)blockIdx.x*256 + threadIdx.x;
  if (i >= (size_t)NROWS*128) return;
  const int row = (int)(i >> 7);
  const int c4 = ((int)(i & 127)) << 2;
  const int b = row / SEQ;
  const int s = row - b*SEQ;
  float4 val;
  if (s == 0) val = *(const float4*)(cls_w + c4);
  else        val = *(const float4*)(x_num + ((size_t)b*512 + (s-1))*512 + c4);
  *(float4*)(x + (size_t)row*DMODEL + c4) = val;
  ushort4 pk;
  pk.x = f2h(val.x); pk.y = f2h(val.y); pk.z = f2h(val.z); pk.w = f2h(val.w);
  *(ushort4*)(xb + (size_t)row*DMODEL + c4) = pk;
}

// ---------------------------------------------------------------------------
// ReGLU: h[n,j] = g[n,j] * relu(g[n,682+j]) for j<682; pad cols 682..703 = 0
// ---------------------------------------------------------------------------
__global__ void reglu_kernel(const ushort* __restrict__ gbuf, ushort* __restrict__ h, int nrows)
{
  const size_t i = (size_t)blockIdx.x*256 + threadIdx.x;
  if (i >= (size_t)nrows*352) return;
  const int row = (int)(i / 352);
  const int pr = (int)(i - (size_t)row*352);
  const int j = pr*2;
  ushort2 res; res.x = 0; res.y = 0;
  if (j < DHID) {
    ushort2 ga = *(const ushort2*)(gbuf + (size_t)row*DH2P + j);
    ushort2 gb = *(const ushort2*)(gbuf + (size_t)row*DH2P + DHID + j);
    res.x = f2h(h2f(ga.x) * fmaxf(h2f(gb.x), 0.f));
    res.y = f2h(h2f(ga.y) * fmaxf(h2f(gb.y), 0.f));
  }
  *(ushort2*)(h + (size_t)row*DHP + j) = res;
}

// ---------------------------------------------------------------------------
// Weight convert fp32 -> fp16 (×scale) with padding.
// ---------------------------------------------------------------------------
__global__ void convert_pad(const float* __restrict__ in, ushort* __restrict__ out,
                            int R, int C, int RP, int CP, int layers, float scale)
{
  const size_t i = (size_t)blockIdx.x*256 + threadIdx.x;
  const size_t per = (size_t)RP*CP;
  if (i >= per*layers) return;
  const int l = (int)(i / per);
  const int rem = (int)(i - (size_t)l*per);
  const int r = rem / CP;
  const int c = rem - r*CP;
  ushort val = 0;
  if (r < R && c < C) val = f2h(in[((size_t)l*R + r)*C + c] * scale);
  out[i] = val;
}

__global__ void pad_bias(const float* __restrict__ in, float* __restrict__ out)
{
  const int i = blockIdx.x*256 + threadIdx.x;
  if (i >= 4*DH2P) return;
  const int l = i / DH2P, j = i - l*DH2P;
  out[i] = (j < DHID2) ? in[l*DHID2 + j] : 0.f;
}

// gather CLS rows: xq = fp16 LN'd CLS rows, xc = fp32 residual CLS rows
__global__ void gather_cls(const ushort* __restrict__ xb, const float* __restrict__ x,
                           ushort* __restrict__ xq, float* __restrict__ xc)
{
  const int b = blockIdx.x, lane = threadIdx.x;
  const size_t src = (size_t)b*SEQ*DMODEL;
  *(short8*)(xq + b*DMODEL + lane*8) = *(const short8*)(xb + src + lane*8);
  *(float4*)(xc + b*DMODEL + lane*8)     = *(const float4*)(x + src + lane*8);
  *(float4*)(xc + b*DMODEL + lane*8 + 4) = *(const float4*)(x + src + lane*8 + 4);
}

// ---------------------------------------------------------------------------
// Last-layer single-query attention: grid B*H, 256 threads. q pre-scaled.
// ---------------------------------------------------------------------------
__global__ __launch_bounds__(256) void attn_decode(
    const ushort* __restrict__ qc, const ushort* __restrict__ k,
    const ushort* __restrict__ v, ushort* __restrict__ oc)
{
  const int bh = blockIdx.x;
  const int b = bh >> 3, h = bh & 7;
  const int t = threadIdx.x;
  __shared__ float sc[SEQ];
  __shared__ float qsh[64];
  __shared__ float red[8];
  __shared__ float osum[256];
  if (t < 64) qsh[t] = h2f(qc[b*DMODEL + h*64 + t]);
  __syncthreads();
  for (int key = t; key < SEQ; key += 256) {
    const ushort* kr = k + ((size_t)b*SEQ + key)*DMODEL + h*64;
    float s = 0.f;
#pragma unroll 8
    for (int d = 0; d < 64; ++d) s += qsh[d]*h2f(kr[d]);
    sc[key] = s;
  }
  __syncthreads();
  float lm = -1e30f;
  for (int key = t; key < SEQ; key += 256) lm = fmaxf(lm, sc[key]);
#pragma unroll
  for (int mask=1; mask<64; mask<<=1) lm = fmaxf(lm, __shfl_xor(lm, mask));
  if ((t&63)==0) red[t>>6] = lm;
  __syncthreads();
  const float mx = fmaxf(fmaxf(red[0],red[1]), fmaxf(red[2],red[3]));
  float ls = 0.f;
  for (int key = t; key < SEQ; key += 256){ float pp = __expf(sc[key]-mx); sc[key]=pp; ls += pp; }
#pragma unroll
  for (int mask=1; mask<64; mask<<=1) ls += __shfl_xor(ls, mask);
  if ((t&63)==0) red[4 + (t>>6)] = ls;
  __syncthreads();
  const float ssum = red[4]+red[5]+red[6]+red[7];
  const int d = t & 63, kc = t >> 6;
  float op = 0.f;
  for (int key = kc; key < SEQ; key += 4)
    op += sc[key] * h2f(v[((size_t)b*SEQ + key)*DMODEL + h*64 + d]);
  osum[t] = op;
  __syncthreads();
  if (t < 64) {
    const float oo = (osum[t]+osum[64+t]+osum[128+t]+osum[192+t]) / ssum;
    oc[b*DMODEL + h*64 + t] = f2h(oo);
  }
}

// final: LN -> relu -> dot(head_w) + head_b. One wave per row.
__global__ void head_kernel(const float* __restrict__ xc, const float* __restrict__ g,
                            const float* __restrict__ be, const float* __restrict__ hw,
                            const float* __restrict__ hb, float* __restrict__ out)
{
  const int row = blockIdx.x;
  const int lane = threadIdx.x;
  const float* xr = xc + (size_t)row*DMODEL;
  float4 a = *(const float4*)(xr + lane*8);
  float4 b = *(const float4*)(xr + lane*8 + 4);
  float s  = a.x+a.y+a.z+a.w+b.x+b.y+b.z+b.w;
  float ss = a.x*a.x+a.y*a.y+a.z*a.z+a.w*a.w+b.x*b.x+b.y*b.y+b.z*b.z+b.w*b.w;
#pragma unroll
  for (int mask=1; mask<64; mask<<=1){ s += __shfl_xor(s,mask); ss += __shfl_xor(ss,mask); }
  const float mu = s*(1.f/512.f);
  const float rstd = rsqrtf(ss*(1.f/512.f) - mu*mu + 1e-5f);
  float vals[8] = {a.x,a.y,a.z,a.w,b.x,b.y,b.z,b.w};
  float acc = 0.f;
#pragma unroll
  for (int j=0;j<8;++j){
    const int c = lane*8 + j;
    float tv = (vals[j]-mu)*rstd*g[c] + be[c];
    acc += fmaxf(tv, 0.f) * hw[c];
  }
#pragma unroll
  for (int mask=1; mask<64; mask<<=1) acc += __shfl_xor(acc, mask);
  if (lane==0) out[row] = acc + hb[0];
}

// ---------------------------------------------------------------------------
extern "C" void kernel_launch(void* const* d_in, const int* in_sizes, int n_in,
                              void* d_out, int out_size, void* d_ws, size_t ws_size,
                              hipStream_t stream)
{
  const float* x_num = (const float*)d_in[0];
  const float* cls_w = (const float*)d_in[1];
  const float* Wq = (const float*)d_in[2];
  const float* bq = (const float*)d_in[3];
  const float* Wk = (const float*)d_in[4];
  const float* bk = (const float*)d_in[5];
  const float* Wv = (const float*)d_in[6];
  const float* bv = (const float*)d_in[7];
  const float* Wo = (const float*)d_in[8];
  const float* bo = (const float*)d_in[9];
  const float* l0_w = (const float*)d_in[10];
  const float* l0_b = (const float*)d_in[11];
  const float* l1_w = (const float*)d_in[12];
  const float* l1_b = (const float*)d_in[13];
  const float* n0_g = (const float*)d_in[14];
  const float* n0_b = (const float*)d_in[15];
  const float* n1_g = (const float*)d_in[16];
  const float* n1_b = (const float*)d_in[17];
  const float* ln_g = (const float*)d_in[18];
  const float* ln_b = (const float*)d_in[19];
  const float* head_w = (const float*)d_in[20];
  const float* head_b = (const float*)d_in[21];
  float* out = (float*)d_out;

  char* p = (char*)d_ws;
  auto alloc = [&](size_t bytes){ char* r = p; p += (bytes + 255) & ~(size_t)255; return r; };

  float* x  = (float*)alloc((size_t)NROWS*DMODEL*4);          // residual fp32
  char* U   = alloc((size_t)NROWS*DHP*2);                     // xb / attn-out / ffn-h
  ushort* xb = (ushort*)U;
  ushort* ob = (ushort*)U;
  ushort* hb = (ushort*)U;
  char* QKVG = alloc((size_t)NROWS*DMODEL*2*3);               // q,k,v; also g
  ushort* qb = (ushort*)QKVG;
  ushort* kb = (ushort*)(QKVG + (size_t)NROWS*DMODEL*2);
  ushort* vb = (ushort*)(QKVG + (size_t)NROWS*DMODEL*2*2);
  ushort* gbuf = (ushort*)QKVG;
  ushort* wqb = (ushort*)alloc((size_t)4*512*512*2);
  ushort* wkb = (ushort*)alloc((size_t)4*512*512*2);
  ushort* wvb = (ushort*)alloc((size_t)4*512*512*2);
  ushort* wob = (ushort*)alloc((size_t)4*512*512*2);
  ushort* l0wp = (ushort*)alloc((size_t)4*DH2P*512*2);
  ushort* l1wp = (ushort*)alloc((size_t)4*512*DHP*2);
  float*  l0bp = (float*)alloc((size_t)4*DH2P*4);
  ushort* xq_cls = (ushort*)alloc(128*512*2);
  float*  xcf = (float*)alloc(128*512*4);
  ushort* qc = (ushort*)alloc(128*512*2);
  ushort* oc = (ushort*)alloc(128*512*2);
  ushort* gc = (ushort*)alloc((size_t)128*DH2P*2);
  ushort* hc = (ushort*)alloc((size_t)128*DHP*2);
  ushort* xcb = (ushort*)alloc(128*512*2);

  auto cdiv = [](size_t a, size_t b){ return (unsigned)((a + b - 1)/b); };

  // weight conversion (fp16, padded; Wq scaled by 1/8 = 1/sqrt(dh))
  convert_pad<<<cdiv((size_t)4*512*512,256),256,0,stream>>>(Wq, wqb, 512,512,512,512,4, 0.125f);
  convert_pad<<<cdiv((size_t)4*512*512,256),256,0,stream>>>(Wk, wkb, 512,512,512,512,4, 1.f);
  convert_pad<<<cdiv((size_t)4*512*512,256),256,0,stream>>>(Wv, wvb, 512,512,512,512,4, 1.f);
  convert_pad<<<cdiv((size_t)4*512*512,256),256,0,stream>>>(Wo, wob, 512,512,512,512,4, 1.f);
  convert_pad<<<cdiv((size_t)4*DH2P*512,256),256,0,stream>>>(l0_w, l0wp, DHID2,512,DH2P,512,4, 1.f);
  convert_pad<<<cdiv((size_t)4*512*DHP,256),256,0,stream>>>(l1_w, l1wp, 512,DHID,512,DHP,4, 1.f);
  pad_bias<<<cdiv(4*DH2P,256),256,0,stream>>>(l0_b, l0bp);

  embed_kernel<<<cdiv((size_t)NROWS*128,256),256,0,stream>>>(x_num, cls_w, x, xb);

  const dim3 g512(4, 513), gl0(11, 513);
  for (int i = 0; i < 3; ++i) {
    if (i > 0)
      ln_kernel<<<cdiv(NROWS,4),256,0,stream>>>(x, n0_g+(size_t)(i-1)*512, n0_b+(size_t)(i-1)*512, xb, NROWS);
    gemm_bt<0><<<g512,256,0,stream>>>(xb, wqb+(size_t)i*262144, bq+i*512, qb, nullptr, 512, 512, 0.125f);
    gemm_bt<0><<<g512,256,0,stream>>>(xb, wkb+(size_t)i*262144, bk+i*512, kb, nullptr, 512, 512, 1.f);
    gemm_bt<0><<<g512,256,0,stream>>>(xb, wvb+(size_t)i*262144, bv+i*512, vb, nullptr, 512, 512, 1.f);
    attn_flash<<<5120,256,0,stream>>>(qb, kb, vb, ob);
    gemm_bt<1><<<g512,256,0,stream>>>(ob, wob+(size_t)i*262144, bo+i*512, nullptr, x, 512, 512, 1.f);
    ln_kernel<<<cdiv(NROWS,4),256,0,stream>>>(x, n1_g+(size_t)i*512, n1_b+(size_t)i*512, xb, NROWS);
    gemm_bt<0><<<gl0,256,0,stream>>>(xb, l0wp+(size_t)i*DH2P*512, l0bp+i*DH2P, gbuf, nullptr, 512, DH2P, 1.f);
    reglu_kernel<<<cdiv((size_t)NROWS*352,256),256,0,stream>>>(gbuf, hb, NROWS);
    gemm_bt<1><<<g512,256,0,stream>>>(hb, l1wp+(size_t)i*512*DHP, l1_b+i*512, nullptr, x, DHP, 512, 1.f);
  }

  // layer 3 (CLS query only)
  ln_kernel<<<cdiv(NROWS,4),256,0,stream>>>(x, n0_g+2*512, n0_b+2*512, xb, NROWS);
  gather_cls<<<128,64,0,stream>>>(xb, x, xq_cls, xcf);
  gemm_bt<0><<<dim3(4,1),256,0,stream>>>(xq_cls, wqb+(size_t)3*262144, bq+3*512, qc, nullptr, 512, 512, 0.125f);
  gemm_bt<0><<<g512,256,0,stream>>>(xb, wkb+(size_t)3*262144, bk+3*512, kb, nullptr, 512, 512, 1.f);
  gemm_bt<0><<<g512,256,0,stream>>>(xb, wvb+(size_t)3*262144, bv+3*512, vb, nullptr, 512, 512, 1.f);
  attn_decode<<<1024,256,0,stream>>>(qc, kb, vb, oc);
  gemm_bt<1><<<dim3(4,1),256,0,stream>>>(oc, wob+(size_t)3*262144, bo+3*512, nullptr, xcf, 512, 512, 1.f);
  ln_kernel<<<cdiv(128,4),256,0,stream>>>(xcf, n1_g+3*512, n1_b+3*512, xcb, 128);
  gemm_bt<0><<<dim3(11,1),256,0,stream>>>(xcb, l0wp+(size_t)3*DH2P*512, l0bp+3*DH2P, gc, nullptr, 512, DH2P, 1.f);
  reglu_kernel<<<cdiv((size_t)128*352,256),256,0,stream>>>(gc, hc, 128);
  gemm_bt<1><<<dim3(4,1),256,0,stream>>>(hc, l1wp+(size_t)3*512*DHP, l1_b+3*512, nullptr, xcf, DHP, 512, 1.f);
  head_kernel<<<128,64,0,stream>>>(xcf, ln_g, ln_b, head_w, head_b, out);
}

// Round 5
// 3014.709 us; speedup vs baseline: 1.2359x; 1.0554x over previous
//
#include <hip/hip_runtime.h>
#include <stdint.h>

typedef __attribute__((ext_vector_type(4))) float f32x4;
typedef __attribute__((ext_vector_type(8))) short short8;
typedef __attribute__((ext_vector_type(8))) _Float16 half8;

#define DMODEL 512
#define SEQ 513
#define BATCH 128
#define NROWS (BATCH*SEQ)   // 65664 = 513 * 128
#define DHID 682
#define DHID2 1364
#define HP 768              // padded per-half FFN width
#define QKVS 1536
#define KVB 64
#define NKT 9
#define QSF 0.1803368801111244f   // 0.125 * log2(e)

__device__ __forceinline__ float h2f(ushort u){ return (float)__builtin_bit_cast(_Float16, u); }
__device__ __forceinline__ ushort f2h(float f){ return __builtin_bit_cast(ushort, (_Float16)f); }
__device__ __forceinline__ f32x4 splat4(float x){ f32x4 v; v[0]=x; v[1]=x; v[2]=x; v[3]=x; return v; }
__device__ __forceinline__ void gload16(const void* g, void* lds){
  __builtin_amdgcn_global_load_lds((const __attribute__((address_space(1))) void*)g,
                                   (__attribute__((address_space(3))) void*)lds, 16, 0, 0);
}

// ---------------------------------------------------------------------------
// GEMM: C[N x O] = A[N x K] @ W[O x K]^T (+bias). fp16 in, fp32 accum.
// EPI=0: write fp16 C (ldc stride). EPI=1: Cf[idx] += acc + bias.
// m97 structure: 128x128 tile, BK=32, 4 waves, global_load_lds width 16.
// ---------------------------------------------------------------------------
template<int EPI>
__global__ __launch_bounds__(256,2) void gemm_bt(
    const ushort* __restrict__ A, const ushort* __restrict__ W,
    const float* __restrict__ bias, ushort* __restrict__ Cb, float* __restrict__ Cf,
    int K, int ldc)
{
  __shared__ ushort As[128*32];
  __shared__ ushort Ws[128*32];
  const int t = threadIdx.x;
  const int lane = t & 63, w = t >> 6;
  const int row0 = blockIdx.y << 7, col0 = blockIdx.x << 7;
  const int wr = (w >> 1) << 6, wc = (w & 1) << 6;
  const int srow = (w << 4) + (lane >> 2);
  const int scol = (lane & 3) << 3;
  const ushort* Ag = A + (size_t)(row0 + srow) * K + scol;
  const ushort* Wg = W + (size_t)(col0 + srow) * K + scol;
  char* AsB = (char*)As;
  char* WsB = (char*)Ws;
  const int ldsw = w << 10;

  f32x4 acc[4][4] = {};

  for (int k0 = 0; k0 < K; k0 += 32) {
    __syncthreads();
    gload16(Ag + k0,                AsB + ldsw);
    gload16(Ag + (size_t)64*K + k0, AsB + 4096 + ldsw);
    gload16(Wg + k0,                WsB + ldsw);
    gload16(Wg + (size_t)64*K + k0, WsB + 4096 + ldsw);
    __syncthreads();
    const int fr = lane & 15, fo = (lane >> 4) << 3;
    half8 af[4], wf[4];
#pragma unroll
    for (int m = 0; m < 4; ++m) af[m] = *(const half8*)&As[(wr + m*16 + fr)*32 + fo];
#pragma unroll
    for (int n = 0; n < 4; ++n) wf[n] = *(const half8*)&Ws[(wc + n*16 + fr)*32 + fo];
#pragma unroll
    for (int m = 0; m < 4; ++m)
#pragma unroll
      for (int n = 0; n < 4; ++n)
        acc[m][n] = __builtin_amdgcn_mfma_f32_16x16x32_f16(af[m], wf[n], acc[m][n], 0, 0, 0);
  }

  const int fr = lane & 15;
  const int r0 = (lane >> 4) << 2;
#pragma unroll
  for (int m = 0; m < 4; ++m) {
    const int rg = row0 + wr + m*16 + r0;
#pragma unroll
    for (int n = 0; n < 4; ++n) {
      const int cg = col0 + wc + n*16 + fr;
      const float bi = bias[cg];
      if (EPI == 0) {
#pragma unroll
        for (int r = 0; r < 4; ++r)
          Cb[(size_t)(rg + r)*ldc + cg] = f2h(acc[m][n][r] + bi);
      } else {
#pragma unroll
        for (int r = 0; r < 4; ++r) {
          const size_t ix = (size_t)(rg + r)*ldc + cg;
          Cf[ix] += acc[m][n][r] + bi;
        }
      }
    }
  }
}

// ---------------------------------------------------------------------------
// Fused FFN-up + ReGLU: H[N x 768] = (A@Wa^T + ba) * relu(A@Wb^T + bb), fp16.
// Two weight tiles per block; A staged once. 32 MFMA per K-step per wave.
// ---------------------------------------------------------------------------
__global__ __launch_bounds__(256,2) void gemm_ffn(
    const ushort* __restrict__ A, const ushort* __restrict__ Wa, const ushort* __restrict__ Wb,
    const float* __restrict__ ba, const float* __restrict__ bb, ushort* __restrict__ H,
    int K, int ldc)
{
  __shared__ ushort As[128*32];
  __shared__ ushort Was[128*32];
  __shared__ ushort Wbs[128*32];
  const int t = threadIdx.x;
  const int lane = t & 63, w = t >> 6;
  const int row0 = blockIdx.y << 7, col0 = blockIdx.x << 7;
  const int wr = (w >> 1) << 6, wc = (w & 1) << 6;
  const int srow = (w << 4) + (lane >> 2);
  const int scol = (lane & 3) << 3;
  const ushort* Ag  = A  + (size_t)(row0 + srow) * K + scol;
  const ushort* WaG = Wa + (size_t)(col0 + srow) * K + scol;
  const ushort* WbG = Wb + (size_t)(col0 + srow) * K + scol;
  const int ldsw = w << 10;

  f32x4 aa[4][4] = {}, ab[4][4] = {};

  for (int k0 = 0; k0 < K; k0 += 32) {
    __syncthreads();
    gload16(Ag + k0,                 (char*)As  + ldsw);
    gload16(Ag + (size_t)64*K + k0,  (char*)As  + 4096 + ldsw);
    gload16(WaG + k0,                (char*)Was + ldsw);
    gload16(WaG + (size_t)64*K + k0, (char*)Was + 4096 + ldsw);
    gload16(WbG + k0,                (char*)Wbs + ldsw);
    gload16(WbG + (size_t)64*K + k0, (char*)Wbs + 4096 + ldsw);
    __syncthreads();
    const int fr = lane & 15, fo = (lane >> 4) << 3;
    half8 af[4], wa[4], wb[4];
#pragma unroll
    for (int m = 0; m < 4; ++m) af[m] = *(const half8*)&As[(wr + m*16 + fr)*32 + fo];
#pragma unroll
    for (int n = 0; n < 4; ++n) {
      wa[n] = *(const half8*)&Was[(wc + n*16 + fr)*32 + fo];
      wb[n] = *(const half8*)&Wbs[(wc + n*16 + fr)*32 + fo];
    }
#pragma unroll
    for (int m = 0; m < 4; ++m)
#pragma unroll
      for (int n = 0; n < 4; ++n) {
        aa[m][n] = __builtin_amdgcn_mfma_f32_16x16x32_f16(af[m], wa[n], aa[m][n], 0, 0, 0);
        ab[m][n] = __builtin_amdgcn_mfma_f32_16x16x32_f16(af[m], wb[n], ab[m][n], 0, 0, 0);
      }
  }

  const int fr = lane & 15;
  const int r0 = (lane >> 4) << 2;
#pragma unroll
  for (int m = 0; m < 4; ++m) {
    const int rg = row0 + wr + m*16 + r0;
#pragma unroll
    for (int n = 0; n < 4; ++n) {
      const int cg = col0 + wc + n*16 + fr;
      const float bav = ba[cg], bbv = bb[cg];
#pragma unroll
      for (int r = 0; r < 4; ++r) {
        const float av = aa[m][n][r] + bav;
        const float bv = ab[m][n][r] + bbv;
        H[(size_t)(rg + r)*ldc + cg] = f2h(av * fmaxf(bv, 0.f));
      }
    }
  }
}

// ---------------------------------------------------------------------------
// Flash attention: swapped QK^T, global_load_lds staging with source swizzle,
// in-LDS V transpose, packed b64 P stores, exp2 softmax (log2e folded into Q).
// qkv layout: [row][1536] = q|k|v. Grid 5120 flat, XCD-chunked.
// ---------------------------------------------------------------------------
__global__ __launch_bounds__(256,4) void attn_flash(
    const ushort* __restrict__ qkv, ushort* __restrict__ o)
{
  const int bid = blockIdx.x;
  const int sw = (bid & 7)*640 + (bid >> 3);
  const int qt = sw % 5;
  const int hb = sw / 5;
  const int h = hb & 7, b = hb >> 3;
  const int t = threadIdx.x, lane = t & 63, w = t >> 6;
  const int fr = lane & 15, g = lane >> 4, gq4 = g << 2;
  const size_t rowB = (size_t)b * SEQ;
  const ushort* q = qkv;
  const ushort* k = qkv + 512;
  const ushort* v = qkv + 1024;

  __shared__ char lds[40960];
  char* const Ks  = lds;
  char* const Vs  = lds + 8192;
  char* const VTs = lds + 16384;
  char* const pb  = lds + 24576 + w*4096;

  const int qr0 = qt*128 + w*32;

  half8 qf[2][2];
#pragma unroll
  for (int nq = 0; nq < 2; ++nq) {
    const int qrow = qr0 + nq*16 + fr;
    const bool ok = qrow < SEQ;
#pragma unroll
    for (int kk = 0; kk < 2; ++kk) {
      half8 val = {};
      if (ok) val = *(const half8*)&q[(rowB + qrow)*QKVS + h*64 + kk*32 + g*8];
      qf[nq][kk] = val;
    }
  }

  f32x4 accO[2][4] = {};
  float mrun[2] = {-1e30f, -1e30f};
  float lrun[2] = {0.f, 0.f};

  const int l8 = lane >> 3, l7 = lane & 7;
  const int chunk = l7 ^ l8;
  auto STAGE = [&](int kt2) {
#pragma unroll
    for (int i = 0; i < 2; ++i) {
      const int row = i*32 + (w<<3) + l8;
      const int keyg = min(kt2*KVB + row, 512);
      const size_t gsrc = (rowB + keyg)*QKVS + h*64 + chunk*8;
      gload16(k + gsrc, Ks + i*4096 + w*1024);
      gload16(v + gsrc, Vs + i*4096 + w*1024);
    }
  };

  const int db  = (lane & 7) | ((w & 1) << 3);
  const int kbq = l8 | ((w & 2) << 2);
  const int d0 = db << 2, key0 = kbq << 2;

  STAGE(0);

  for (int kt = 0; kt < NKT; ++kt) {
    __syncthreads();

    // ---- QK^T swapped: sc[mk][nq], key = mk*16 + gq4 + r, q = nq*16 + fr
    f32x4 sc[4][2] = {};
#pragma unroll
    for (int kk = 0; kk < 2; ++kk) {
      half8 kf[4];
#pragma unroll
      for (int mk = 0; mk < 4; ++mk) {
        const int row = mk*16 + fr;
        kf[mk] = *(const half8*)(Ks + row*128 + ((kk*64 + g*16) ^ ((fr&7)<<4)));
      }
#pragma unroll
      for (int mk = 0; mk < 4; ++mk)
#pragma unroll
        for (int nq = 0; nq < 2; ++nq)
          sc[mk][nq] = __builtin_amdgcn_mfma_f32_16x16x32_f16(kf[mk], qf[nq][kk], sc[mk][nq], 0, 0, 0);
    }

    // ---- in-LDS V transpose
    {
      uint2 a[4];
#pragma unroll
      for (int i = 0; i < 4; ++i) {
        const int row = key0 + i;
        a[i] = *(const uint2*)(Vs + row*128 + ((d0*2) ^ ((row&7)<<4)));
      }
      uint2 bb[4];
      bb[0].x = (a[0].x & 0xffffu) | (a[1].x << 16);
      bb[0].y = (a[2].x & 0xffffu) | (a[3].x << 16);
      bb[1].x = (a[0].x >> 16) | (a[1].x & 0xffff0000u);
      bb[1].y = (a[2].x >> 16) | (a[3].x & 0xffff0000u);
      bb[2].x = (a[0].y & 0xffffu) | (a[1].y << 16);
      bb[2].y = (a[2].y & 0xffffu) | (a[3].y << 16);
      bb[3].x = (a[0].y >> 16) | (a[1].y & 0xffff0000u);
      bb[3].y = (a[2].y >> 16) | (a[3].y & 0xffff0000u);
#pragma unroll
      for (int j = 0; j < 4; ++j) {
        const int drow = d0 + j;
        *(uint2*)(VTs + drow*128 + ((key0*2) ^ ((drow&7)<<4))) = bb[j];
      }
    }

    if (kt == NKT-1) {
#pragma unroll
      for (int mk = 0; mk < 4; ++mk)
#pragma unroll
        for (int r = 0; r < 4; ++r)
          if (mk + gq4 + r) { sc[mk][0][r] = -1e30f; sc[mk][1][r] = -1e30f; }
    }

    __syncthreads();

    if (kt+1 < NKT) STAGE(kt+1);

    // ---- online softmax (exp2 domain)
    float al2[2];
#pragma unroll
    for (int nq = 0; nq < 2; ++nq) {
      float tm = sc[0][nq][0];
#pragma unroll
      for (int mk = 0; mk < 4; ++mk)
#pragma unroll
        for (int r = 0; r < 4; ++r) tm = fmaxf(tm, sc[mk][nq][r]);
      tm = fmaxf(tm, __shfl_xor(tm, 16));
      tm = fmaxf(tm, __shfl_xor(tm, 32));
      const float mnew = fmaxf(mrun[nq], tm);
      const float al = exp2f(mrun[nq] - mnew);
      mrun[nq] = mnew;
      float rs = 0.f;
#pragma unroll
      for (int mk = 0; mk < 4; ++mk)
#pragma unroll
        for (int r = 0; r < 4; ++r) {
          const float pv = exp2f(sc[mk][nq][r] - mnew);
          sc[mk][nq][r] = pv;
          rs += pv;
        }
      rs += __shfl_xor(rs, 16);
      rs += __shfl_xor(rs, 32);
      lrun[nq] = lrun[nq]*al + rs;
      al2[nq] = al;
      char* prow = pb + (nq*16 + fr)*128;
#pragma unroll
      for (int mk = 0; mk < 4; ++mk) {
        uint2 pk;
        pk.x = (uint)f2h(sc[mk][nq][0]) | ((uint)f2h(sc[mk][nq][1]) << 16);
        pk.y = (uint)f2h(sc[mk][nq][2]) | ((uint)f2h(sc[mk][nq][3]) << 16);
        *(uint2*)(prow + ((mk*32 + gq4*2) ^ ((fr&7)<<4))) = pk;
      }
    }

#pragma unroll
    for (int mq = 0; mq < 2; ++mq)
#pragma unroll
      for (int r = 0; r < 4; ++r) {
        const float alr = __shfl(al2[mq], (lane & 48) | (gq4 + r));
#pragma unroll
        for (int dn = 0; dn < 4; ++dn) accO[mq][dn][r] *= alr;
      }

    asm volatile("" ::: "memory");

    // ---- PV
#pragma unroll
    for (int kk2 = 0; kk2 < 2; ++kk2) {
      half8 pf[2];
#pragma unroll
      for (int mq = 0; mq < 2; ++mq)
        pf[mq] = *(const half8*)(pb + (mq*16 + fr)*128 + ((kk2*64 + g*16) ^ ((fr&7)<<4)));
      half8 vf[4];
#pragma unroll
      for (int dn = 0; dn < 4; ++dn) {
        const int row = dn*16 + fr;
        vf[dn] = *(const half8*)(VTs + row*128 + ((kk2*64 + g*16) ^ ((fr&7)<<4)));
      }
#pragma unroll
      for (int mq = 0; mq < 2; ++mq)
#pragma unroll
        for (int dn = 0; dn < 4; ++dn)
          accO[mq][dn] = __builtin_amdgcn_mfma_f32_16x16x32_f16(pf[mq], vf[dn], accO[mq][dn], 0, 0, 0);
    }
  }

#pragma unroll
  for (int mq = 0; mq < 2; ++mq)
#pragma unroll
    for (int r = 0; r < 4; ++r) {
      const int qrow = qr0 + mq*16 + gq4 + r;
      const float ls = __shfl(lrun[mq], (lane & 48) | (gq4 + r));
      if (qrow < SEQ) {
        const float inv = 1.f / ls;
#pragma unroll
        for (int dn = 0; dn < 4; ++dn)
          o[(rowB + qrow)*DMODEL + h*64 + dn*16 + fr] = f2h(accO[mq][dn][r] * inv);
      }
    }
}

// ---------------------------------------------------------------------------
__global__ __launch_bounds__(256) void ln_kernel(
    const float* __restrict__ x, const float* __restrict__ gamma, const float* __restrict__ beta,
    ushort* __restrict__ out, int nrows)
{
  const int row = blockIdx.x*4 + (threadIdx.x >> 6);
  const int lane = threadIdx.x & 63;
  if (row >= nrows) return;
  const float* xr = x + (size_t)row*DMODEL;
  float4 a = *(const float4*)(xr + lane*8);
  float4 b = *(const float4*)(xr + lane*8 + 4);
  float s  = a.x+a.y+a.z+a.w+b.x+b.y+b.z+b.w;
  float ss = a.x*a.x+a.y*a.y+a.z*a.z+a.w*a.w+b.x*b.x+b.y*b.y+b.z*b.z+b.w*b.w;
#pragma unroll
  for (int mask=1; mask<64; mask<<=1){ s += __shfl_xor(s,mask); ss += __shfl_xor(ss,mask); }
  const float mu = s*(1.f/512.f);
  const float rstd = rsqrtf(ss*(1.f/512.f) - mu*mu + 1e-5f);
  float vals[8] = {a.x,a.y,a.z,a.w,b.x,b.y,b.z,b.w};
  short8 pk;
#pragma unroll
  for (int j=0;j<8;++j){
    const int c = lane*8 + j;
    pk[j] = (short)f2h((vals[j]-mu)*rstd*gamma[c] + beta[c]);
  }
  *(short8*)(out + (size_t)row*DMODEL + lane*8) = pk;
}

// ---------------------------------------------------------------------------
__global__ void embed_kernel(const float* __restrict__ x_num, const float* __restrict__ cls_w,
                             float* __restrict__ x, ushort* __restrict__ xb)
{
  const size_t i = (size_t)blockIdx.x*256 + threadIdx.x;
  if (i >= (size_t)NROWS*128) return;
  const int row = (int)(i >> 7);
  const int c4 = ((int)(i & 127)) << 2;
  const int b = row / SEQ;
  const int s = row - b*SEQ;
  float4 val;
  if (s == 0) val = *(const float4*)(cls_w + c4);
  else        val = *(const float4*)(x_num + ((size_t)b*512 + (s-1))*512 + c4);
  *(float4*)(x + (size_t)row*DMODEL + c4) = val;
  ushort4 pk;
  pk.x = f2h(val.x); pk.y = f2h(val.y); pk.z = f2h(val.z); pk.w = f2h(val.w);
  *(ushort4*)(xb + (size_t)row*DMODEL + c4) = pk;
}

// ---------------------------------------------------------------------------
// Weight convert fp32 -> fp16 (×scale) with padding, src row offset, out stride.
// ---------------------------------------------------------------------------
__global__ void convert_pad(const float* __restrict__ in, ushort* __restrict__ out,
                            int R, int C, int RP, int CP, int layers, float scale,
                            int r0, int srcRL, size_t ostride)
{
  const size_t i = (size_t)blockIdx.x*256 + threadIdx.x;
  const size_t per = (size_t)RP*CP;
  if (i >= per*layers) return;
  const int l = (int)(i / per);
  const int rem = (int)(i - (size_t)l*per);
  const int r = rem / CP;
  const int c = rem - r*CP;
  ushort val = 0;
  if (r < R && c < C) val = f2h(in[((size_t)l*srcRL + r0 + r)*C + c] * scale);
  out[(size_t)l*ostride + (size_t)r*CP + c] = val;
}

// fused bias builders: qkv bias [4][1536], ffn a/b biases [4][768]
__global__ void build_bias(const float* __restrict__ bq, const float* __restrict__ bk,
                           const float* __restrict__ bv, const float* __restrict__ l0b,
                           float* __restrict__ fqkv, float* __restrict__ fa, float* __restrict__ fb)
{
  const int i = blockIdx.x*256 + threadIdx.x;
  if (i < 4*1536) {
    const int l = i / 1536, j = i - l*1536;
    float val;
    if (j < 512)       val = bq[l*512 + j] * QSF;
    else if (j < 1024) val = bk[l*512 + j - 512];
    else               val = bv[l*512 + j - 1024];
    fqkv[i] = val;
  }
  if (i < 4*HP) {
    const int l = i / HP, j = i - l*HP;
    fa[i] = (j < DHID) ? l0b[l*DHID2 + j] : 0.f;
    fb[i] = (j < DHID) ? l0b[l*DHID2 + DHID + j] : 0.f;
  }
}

// gather CLS rows
__global__ void gather_cls(const ushort* __restrict__ xb, const float* __restrict__ x,
                           ushort* __restrict__ xq, float* __restrict__ xc)
{
  const int b = blockIdx.x, lane = threadIdx.x;
  const size_t src = (size_t)b*SEQ*DMODEL;
  *(short8*)(xq + b*DMODEL + lane*8) = *(const short8*)(xb + src + lane*8);
  *(float4*)(xc + b*DMODEL + lane*8)     = *(const float4*)(x + src + lane*8);
  *(float4*)(xc + b*DMODEL + lane*8 + 4) = *(const float4*)(x + src + lane*8 + 4);
}

// ---------------------------------------------------------------------------
// Last-layer single-query attention (exp2 domain; q pre-scaled incl. log2e).
// k,v point into qkv (row stride QKVS). qc stride 512.
// ---------------------------------------------------------------------------
__global__ __launch_bounds__(256) void attn_decode(
    const ushort* __restrict__ qc, const ushort* __restrict__ k,
    const ushort* __restrict__ v, ushort* __restrict__ oc)
{
  const int bh = blockIdx.x;
  const int b = bh >> 3, h = bh & 7;
  const int t = threadIdx.x;
  __shared__ float sc[SEQ];
  __shared__ float qsh[64];
  __shared__ float red[8];
  __shared__ float osum[256];
  if (t < 64) qsh[t] = h2f(qc[b*DMODEL + h*64 + t]);
  __syncthreads();
  for (int key = t; key < SEQ; key += 256) {
    const ushort* kr = k + ((size_t)b*SEQ + key)*QKVS + h*64;
    float s = 0.f;
#pragma unroll 8
    for (int d = 0; d < 64; ++d) s += qsh[d]*h2f(kr[d]);
    sc[key] = s;
  }
  __syncthreads();
  float lm = -1e30f;
  for (int key = t; key < SEQ; key += 256) lm = fmaxf(lm, sc[key]);
#pragma unroll
  for (int mask=1; mask<64; mask<<=1) lm = fmaxf(lm, __shfl_xor(lm, mask));
  if ((t&63)==0) red[t>>6] = lm;
  __syncthreads();
  const float mx = fmaxf(fmaxf(red[0],red[1]), fmaxf(red[2],red[3]));
  float ls = 0.f;
  for (int key = t; key < SEQ; key += 256){ float pp = exp2f(sc[key]-mx); sc[key]=pp; ls += pp; }
#pragma unroll
  for (int mask=1; mask<64; mask<<=1) ls += __shfl_xor(ls, mask);
  if ((t&63)==0) red[4 + (t>>6)] = ls;
  __syncthreads();
  const float ssum = red[4]+red[5]+red[6]+red[7];
  const int d = t & 63, kc = t >> 6;
  float op = 0.f;
  for (int key = kc; key < SEQ; key += 4)
    op += sc[key] * h2f(v[((size_t)b*SEQ + key)*QKVS + h*64 + d]);
  osum[t] = op;
  __syncthreads();
  if (t < 64) {
    const float oo = (osum[t]+osum[64+t]+osum[128+t]+osum[192+t]) / ssum;
    oc[b*DMODEL + h*64 + t] = f2h(oo);
  }
}

// final: LN -> relu -> dot(head_w) + head_b
__global__ void head_kernel(const float* __restrict__ xc, const float* __restrict__ g,
                            const float* __restrict__ be, const float* __restrict__ hw,
                            const float* __restrict__ hb, float* __restrict__ out)
{
  const int row = blockIdx.x;
  const int lane = threadIdx.x;
  const float* xr = xc + (size_t)row*DMODEL;
  float4 a = *(const float4*)(xr + lane*8);
  float4 b = *(const float4*)(xr + lane*8 + 4);
  float s  = a.x+a.y+a.z+a.w+b.x+b.y+b.z+b.w;
  float ss = a.x*a.x+a.y*a.y+a.z*a.z+a.w*a.w+b.x*b.x+b.y*b.y+b.z*b.z+b.w*b.w;
#pragma unroll
  for (int mask=1; mask<64; mask<<=1){ s += __shfl_xor(s,mask); ss += __shfl_xor(ss,mask); }
  const float mu = s*(1.f/512.f);
  const float rstd = rsqrtf(ss*(1.f/512.f) - mu*mu + 1e-5f);
  float vals[8] = {a.x,a.y,a.z,a.w,b.x,b.y,b.z,b.w};
  float acc = 0.f;
#pragma unroll
  for (int j=0;j<8;++j){
    const int c = lane*8 + j;
    float tv = (vals[j]-mu)*rstd*g[c] + be[c];
    acc += fmaxf(tv, 0.f) * hw[c];
  }
#pragma unroll
  for (int mask=1; mask<64; mask<<=1) acc += __shfl_xor(acc, mask);
  if (lane==0) out[row] = acc + hb[0];
}

// ---------------------------------------------------------------------------
extern "C" void kernel_launch(void* const* d_in, const int* in_sizes, int n_in,
                              void* d_out, int out_size, void* d_ws, size_t ws_size,
                              hipStream_t stream)
{
  const float* x_num = (const float*)d_in[0];
  const float* cls_w = (const float*)d_in[1];
  const float* Wq = (const float*)d_in[2];
  const float* bq = (const float*)d_in[3];
  const float* Wk = (const float*)d_in[4];
  const float* bk = (const float*)d_in[5];
  const float* Wv = (const float*)d_in[6];
  const float* bv = (const float*)d_in[7];
  const float* Wo = (const float*)d_in[8];
  const float* bo = (const float*)d_in[9];
  const float* l0_w = (const float*)d_in[10];
  const float* l0_b = (const float*)d_in[11];
  const float* l1_w = (const float*)d_in[12];
  const float* l1_b = (const float*)d_in[13];
  const float* n0_g = (const float*)d_in[14];
  const float* n0_b = (const float*)d_in[15];
  const float* n1_g = (const float*)d_in[16];
  const float* n1_b = (const float*)d_in[17];
  const float* ln_g = (const float*)d_in[18];
  const float* ln_b = (const float*)d_in[19];
  const float* head_w = (const float*)d_in[20];
  const float* head_b = (const float*)d_in[21];
  float* out = (float*)d_out;

  char* p = (char*)d_ws;
  auto alloc = [&](size_t bytes){ char* r = p; p += (bytes + 255) & ~(size_t)255; return r; };

  float* x  = (float*)alloc((size_t)NROWS*DMODEL*4);          // residual fp32
  char* U   = alloc((size_t)NROWS*DMODEL*2);                  // xb / attn-out
  ushort* xb = (ushort*)U;
  ushort* ob = (ushort*)U;
  char* QKVG = alloc((size_t)NROWS*QKVS*2);                   // qkv; also h [NROWS][768]
  ushort* qkv = (ushort*)QKVG;
  ushort* hbuf = (ushort*)QKVG;
  ushort* wqkvb = (ushort*)alloc((size_t)4*QKVS*512*2);
  ushort* wob  = (ushort*)alloc((size_t)4*512*512*2);
  ushort* wl0a = (ushort*)alloc((size_t)4*HP*512*2);
  ushort* wl0b = (ushort*)alloc((size_t)4*HP*512*2);
  ushort* l1wp = (ushort*)alloc((size_t)4*512*HP*2);
  float*  fqkvb = (float*)alloc((size_t)4*QKVS*4);
  float*  l0ba = (float*)alloc((size_t)4*HP*4);
  float*  l0bb = (float*)alloc((size_t)4*HP*4);
  ushort* xq_cls = (ushort*)alloc(128*512*2);
  float*  xcf = (float*)alloc(128*512*4);
  ushort* qc = (ushort*)alloc(128*512*2);
  ushort* oc = (ushort*)alloc(128*512*2);
  ushort* hc = (ushort*)alloc((size_t)128*HP*2);
  ushort* xcb = (ushort*)alloc(128*512*2);

  auto cdiv = [](size_t a, size_t b){ return (unsigned)((a + b - 1)/b); };

  // weight conversion: fused QKV [1536x512] per layer (q-part scaled by QSF)
  convert_pad<<<cdiv((size_t)4*512*512,256),256,0,stream>>>(Wq, wqkvb,            512,512,512,512,4, QSF, 0, 512, (size_t)QKVS*512);
  convert_pad<<<cdiv((size_t)4*512*512,256),256,0,stream>>>(Wk, wqkvb + 512*512,  512,512,512,512,4, 1.f, 0, 512, (size_t)QKVS*512);
  convert_pad<<<cdiv((size_t)4*512*512,256),256,0,stream>>>(Wv, wqkvb + 1024*512, 512,512,512,512,4, 1.f, 0, 512, (size_t)QKVS*512);
  convert_pad<<<cdiv((size_t)4*512*512,256),256,0,stream>>>(Wo, wob, 512,512,512,512,4, 1.f, 0, 512, (size_t)512*512);
  convert_pad<<<cdiv((size_t)4*HP*512,256),256,0,stream>>>(l0_w, wl0a, DHID,512,HP,512,4, 1.f, 0,    DHID2, (size_t)HP*512);
  convert_pad<<<cdiv((size_t)4*HP*512,256),256,0,stream>>>(l0_w, wl0b, DHID,512,HP,512,4, 1.f, DHID, DHID2, (size_t)HP*512);
  convert_pad<<<cdiv((size_t)4*512*HP,256),256,0,stream>>>(l1_w, l1wp, 512,DHID,512,HP,4, 1.f, 0, 512, (size_t)512*HP);
  build_bias<<<cdiv(4*QKVS,256),256,0,stream>>>(bq, bk, bv, l0_b, fqkvb, l0ba, l0bb);

  embed_kernel<<<cdiv((size_t)NROWS*128,256),256,0,stream>>>(x_num, cls_w, x, xb);

  const dim3 gqkv(12, 513), g512(4, 513), gffn(6, 513);
  for (int i = 0; i < 3; ++i) {
    if (i > 0)
      ln_kernel<<<cdiv(NROWS,4),256,0,stream>>>(x, n0_g+(size_t)(i-1)*512, n0_b+(size_t)(i-1)*512, xb, NROWS);
    gemm_bt<0><<<gqkv,256,0,stream>>>(xb, wqkvb+(size_t)i*QKVS*512, fqkvb+(size_t)i*QKVS, qkv, nullptr, 512, QKVS);
    attn_flash<<<5120,256,0,stream>>>(qkv, ob);
    gemm_bt<1><<<g512,256,0,stream>>>(ob, wob+(size_t)i*262144, bo+i*512, nullptr, x, 512, 512);
    ln_kernel<<<cdiv(NROWS,4),256,0,stream>>>(x, n1_g+(size_t)i*512, n1_b+(size_t)i*512, xb, NROWS);
    gemm_ffn<<<gffn,256,0,stream>>>(xb, wl0a+(size_t)i*HP*512, wl0b+(size_t)i*HP*512,
                                    l0ba+(size_t)i*HP, l0bb+(size_t)i*HP, hbuf, 512, HP);
    gemm_bt<1><<<g512,256,0,stream>>>(hbuf, l1wp+(size_t)i*512*HP, l1_b+i*512, nullptr, x, HP, 512);
  }

  // layer 3 (CLS query only)
  ln_kernel<<<cdiv(NROWS,4),256,0,stream>>>(x, n0_g+2*512, n0_b+2*512, xb, NROWS);
  gather_cls<<<128,64,0,stream>>>(xb, x, xq_cls, xcf);
  gemm_bt<0><<<dim3(4,1),256,0,stream>>>(xq_cls, wqkvb+(size_t)3*QKVS*512, fqkvb+(size_t)3*QKVS, qc, nullptr, 512, 512);
  gemm_bt<0><<<dim3(8,513),256,0,stream>>>(xb, wqkvb+(size_t)3*QKVS*512 + 512*512, fqkvb+(size_t)3*QKVS + 512,
                                           qkv + 512, nullptr, 512, QKVS);
  attn_decode<<<1024,256,0,stream>>>(qc, qkv + 512, qkv + 1024, oc);
  gemm_bt<1><<<dim3(4,1),256,0,stream>>>(oc, wob+(size_t)3*262144, bo+3*512, nullptr, xcf, 512, 512);
  ln_kernel<<<cdiv(128,4),256,0,stream>>>(xcf, n1_g+3*512, n1_b+3*512, xcb, 128);
  gemm_ffn<<<dim3(6,1),256,0,stream>>>(xcb, wl0a+(size_t)3*HP*512, wl0b+(size_t)3*HP*512,
                                       l0ba+(size_t)3*HP, l0bb+(size_t)3*HP, hc, 512, HP);
  gemm_bt<1><<<dim3(4,1),256,0,stream>>>(hc, l1wp+(size_t)3*512*HP, l1_b+3*512, nullptr, xcf, HP, 512);
  head_kernel<<<128,64,0,stream>>>(xcf, ln_g, ln_b, head_w, head_b, out);
}